// Round 1
// baseline (2077.186 us; speedup 1.0000x reference)
//
#include <hip/hip_runtime.h>
#include <stdint.h>

#define BATCH 8
#define HEADS 8
#define HM 128
#define WM 128
#define NPIX (HM*WM)      // 16384
#define DIMC 128
#define DH 64
#define GS 64
#define INNER 512
#define KTOT 1152         // 9*128 folded conv K
#define CS_LD 132         // fp32 row pad: 528 B/row, 16B-aligned, 2-way banks
#define SW_LD 136         // u16 row pad: 272 B/row, 16B-aligned

typedef unsigned short u16;
typedef short v8s __attribute__((ext_vector_type(8)));   // 8 bf16 in 4 VGPRs
typedef float v4f __attribute__((ext_vector_type(4)));   // MFMA accum

__device__ __forceinline__ u16 f2bf(float f) {
    unsigned x = __float_as_uint(f);
    return (u16)((x + 0x7fffu + ((x >> 16) & 1u)) >> 16);   // RNE
}
__device__ __forceinline__ float bf2f(u16 u) { return __uint_as_float(((unsigned)u) << 16); }

struct alignas(8) US4 { u16 x, y, z, w; };
union BF8 { uint4 v; u16 s[8]; };

// ---------------------------------------------------------------------------
// Build folded logit weights, TRANSPOSED + bf16:
//   wcatT[co][k=s*128+ci] = (sum_c conv_x_w[k][h*64+c]*slice_w[g][c]) / clip(temp)
// Also emit wfxT[co][k] = bf16(conv_fx_w[k][co]) (transposed for MFMA B-frags).
// ---------------------------------------------------------------------------
__global__ __launch_bounds__(256) void k_build_w(
    const float* __restrict__ wx, const float* __restrict__ wfx,
    const float* __restrict__ slw, const float* __restrict__ temp,
    u16* __restrict__ wcatT, u16* __restrict__ wfxT)
{
    __shared__ float sw_l[GS][DH + 1];
    __shared__ float wx_l[INNER];
    int row = blockIdx.x;            // 0..1151
    int t = threadIdx.x;
    for (int i = t; i < GS * DH; i += 256) sw_l[i >> 6][i & 63] = slw[i];
    for (int i = t; i < INNER; i += 256) wx_l[i] = wx[(size_t)row * INNER + i];
    __syncthreads();
#pragma unroll
    for (int j = 0; j < 2; j++) {
        int co = j * 256 + t;
        int h = co >> 6, g = co & 63;
        float s = 0.f;
        for (int c = 0; c < DH; c++) s = fmaf(wx_l[h * 64 + c], sw_l[g][c], s);
        float tv = fminf(fmaxf(temp[h], 0.1f), 5.0f);
        wcatT[(size_t)co * KTOT + row] = f2bf(s / tv);
        wfxT[(size_t)co * KTOT + row] = f2bf(wfx[(size_t)row * INNER + co]);
    }
}

__global__ __launch_bounds__(512) void k_build_b(
    const float* __restrict__ bx, const float* __restrict__ slw,
    const float* __restrict__ slb, const float* __restrict__ temp,
    float* __restrict__ bcatL)
{
    int co = threadIdx.x;            // 0..511
    int h = co >> 6, g = co & 63;
    float s = slb[g];
    for (int c = 0; c < DH; c++) s = fmaf(bx[h * 64 + c], slw[g * 64 + c], s);
    float tv = fminf(fmaxf(temp[h], 0.1f), 5.0f);
    bcatL[co] = s / tv;
}

// ---------------------------------------------------------------------------
// Shared MFMA conv core: one 128px (one y-row) x 128ch tile, K = 9 taps x 128.
// A/B staged bf16 in LDS rows padded to 72 elems (144 B, uniform banks).
// 4 waves: wave (wr,wc) owns a 64x64 output quadrant as 4x4 16x16 fragments.
//   A-frag: lane holds A[m=lane&15][k=8*(lane>>4)+r]  (m relative to frag)
//   B-frag: lane holds B[k=8*(lane>>4)+r][n=lane&15]
//   C/D:    [row=(lane>>4)*4+q][col=lane&15]          (verified layout)
// ---------------------------------------------------------------------------
__device__ __forceinline__ void conv_core(
    const float* __restrict__ xin, const u16* __restrict__ wT,
    u16* __restrict__ Asm, u16* __restrict__ Bsm,
    int b, int y, int cob, int t, v4f acc[4][4])
{
    int arow = t >> 1, half = t & 1;       // staging role: row 0..127, 32-elem half
    int lane = t & 63;
    int l16 = lane & 15, lk = lane >> 4;
    int wave = t >> 6, wr = wave >> 1, wc = wave & 1;

    for (int ky = 0; ky < 3; ky++) {
        int yy = y + ky - 1;
        bool yok = (unsigned)yy < (unsigned)HM;
        for (int kx = 0; kx < 3; kx++) {
            int col = arow + kx - 1;
            bool ok = yok && ((unsigned)col < (unsigned)WM);
            const float* srcb = xin + (((size_t)b * NPIX + (size_t)yy * WM + col) * DIMC);
            int s = ky * 3 + kx;
            const u16* wbase = wT + (size_t)(cob + arow) * KTOT + s * DIMC;
            for (int ci0 = 0; ci0 < DIMC; ci0 += 64) {
                __syncthreads();
                // ---- A stage: x fp32 -> bf16 on the fly (32 elems/thread) ----
                BF8 o[4];
                if (ok) {
                    const float4* p = (const float4*)(srcb + ci0 + half * 32);
#pragma unroll
                    for (int u = 0; u < 4; u++) {
                        float4 fa = p[2 * u], fb = p[2 * u + 1];
                        o[u].s[0] = f2bf(fa.x); o[u].s[1] = f2bf(fa.y);
                        o[u].s[2] = f2bf(fa.z); o[u].s[3] = f2bf(fa.w);
                        o[u].s[4] = f2bf(fb.x); o[u].s[5] = f2bf(fb.y);
                        o[u].s[6] = f2bf(fb.z); o[u].s[7] = f2bf(fb.w);
                    }
                } else {
#pragma unroll
                    for (int u = 0; u < 4; u++) o[u].v = make_uint4(0u, 0u, 0u, 0u);
                }
                u16* ad = Asm + arow * 72 + half * 32;
#pragma unroll
                for (int u = 0; u < 4; u++) *(uint4*)(ad + u * 8) = o[u].v;
                // ---- B stage: bf16 copy from transposed weights ----
                const u16* wp = wbase + ci0 + half * 32;
                u16* bd = Bsm + arow * 72 + half * 32;
#pragma unroll
                for (int u = 0; u < 4; u++) *(uint4*)(bd + u * 8) = *(const uint4*)(wp + u * 8);
                __syncthreads();
                // ---- 2 x (8 frag reads + 16 MFMA) ----
#pragma unroll
                for (int ks = 0; ks < 2; ks++) {
                    v8s av[4], bv[4];
#pragma unroll
                    for (int mi = 0; mi < 4; mi++)
                        av[mi] = *(const v8s*)(Asm + (wr * 64 + mi * 16 + l16) * 72 + ks * 32 + lk * 8);
#pragma unroll
                    for (int nj = 0; nj < 4; nj++)
                        bv[nj] = *(const v8s*)(Bsm + (wc * 64 + nj * 16 + l16) * 72 + ks * 32 + lk * 8);
#pragma unroll
                    for (int mi = 0; mi < 4; mi++)
#pragma unroll
                        for (int nj = 0; nj < 4; nj++)
                            acc[mi][nj] = __builtin_amdgcn_mfma_f32_16x16x32_bf16(
                                av[mi], bv[nj], acc[mi][nj], 0, 0, 0);
                }
            }
        }
    }
}

// ---------------------------------------------------------------------------
// Pass L: MFMA conv -> 512 logit channels; fused per-pixel softmax per head;
// sw stored bf16; slice_norm via one atomic per (h,g) per block.
// ---------------------------------------------------------------------------
union SmemCL {
    struct { u16 A[128 * 72]; u16 B[128 * 72]; } c;   // 36 KiB conv tiles
    float Cs[64][CS_LD];                              // 33 KiB epilogue
};

__global__ __launch_bounds__(256) void k_convL(
    const float* __restrict__ xin, const u16* __restrict__ wcatT,
    const float* __restrict__ bcatL, u16* __restrict__ swb, float* __restrict__ norm)
{
    __shared__ SmemCL sm;
    int pt = blockIdx.x;             // 0..1023 = b*128 + y
    int b = pt >> 7, y = pt & 127;
    int ct = blockIdx.y;             // heads 2ct, 2ct+1
    int cob = ct << 7;
    int t = threadIdx.x;
    int lane = t & 63, wave = t >> 6;
    int wr = wave >> 1, wc = wave & 1;
    int l16 = lane & 15, lk = lane >> 4;

    v4f acc[4][4];
#pragma unroll
    for (int i = 0; i < 4; i++)
#pragma unroll
        for (int j = 0; j < 4; j++) acc[i][j] = v4f{0.f, 0.f, 0.f, 0.f};

    conv_core(xin, wcatT, sm.c.A, sm.c.B, b, y, cob, t, acc);
    __syncthreads();   // conv done; Cs aliases A/B

    float bb[4];
#pragma unroll
    for (int nj = 0; nj < 4; nj++) bb[nj] = bcatL[cob + wc * 64 + nj * 16 + l16];

    float normacc = 0.f;
    for (int s2 = 0; s2 < 2; s2++) {          // pixel halves: waves wr==s2 own them
        if (wr == s2) {
#pragma unroll
            for (int mi = 0; mi < 4; mi++)
#pragma unroll
                for (int nj = 0; nj < 4; nj++)
#pragma unroll
                    for (int q = 0; q < 4; q++)
                        sm.Cs[mi * 16 + lk * 4 + q][wc * 64 + nj * 16 + l16] =
                            acc[mi][nj][q] + bb[nj];
        }
        __syncthreads();
        if (t < 128) {                        // one (pixel, head) softmax per thread
            int p = t & 63, h = t >> 6;
            float mx = -1e30f;
            for (int j = 0; j < 64; j++) mx = fmaxf(mx, sm.Cs[p][h * 64 + j]);
            float ssum = 0.f;
            for (int j = 0; j < 64; j++) {
                float e = __expf(sm.Cs[p][h * 64 + j] - mx);
                sm.Cs[p][h * 64 + j] = e; ssum += e;
            }
            float inv = 1.f / ssum;
            for (int j = 0; j < 64; j++) sm.Cs[p][h * 64 + j] *= inv;
        }
        __syncthreads();
        if (t < 128) {                        // column-reduce for slice_norm
            float sacc = 0.f;
            for (int p = 0; p < 64; p++) sacc += sm.Cs[p][t];
            normacc += sacc;
        }
#pragma unroll
        for (int it = 0; it < 8; it++) {      // coalesced bf16 store of sw
            int q = it * 256 + t;             // 0..2047
            int hv = q >> 10, qq = q & 1023;
            int p = qq >> 4, gq = (qq & 15) * 4;
            US4 r;
            r.x = f2bf(sm.Cs[p][hv * 64 + gq + 0]);
            r.y = f2bf(sm.Cs[p][hv * 64 + gq + 1]);
            r.z = f2bf(sm.Cs[p][hv * 64 + gq + 2]);
            r.w = f2bf(sm.Cs[p][hv * 64 + gq + 3]);
            size_t idx = (((size_t)(b * HEADS + 2 * ct + hv) * NPIX) + (size_t)y * WM + s2 * 64 + p) * GS + gq;
            *(US4*)&swb[idx] = r;
        }
        __syncthreads();
    }
    if (t < 128) {
        int h = t >> 6, g = t & 63;
        atomicAdd(&norm[(b * HEADS + 2 * ct + h) * GS + g], normacc);
    }
}

// ---------------------------------------------------------------------------
// Pass F: MFMA conv -> 512 fx channels; epilogue pools against sw (bf16)
// into slice_token partials. 4 y-rows per block to amortize straw atomics.
// ---------------------------------------------------------------------------
union SmemCF {
    struct { u16 A[128 * 72]; u16 B[128 * 72]; } c;            // 36 KiB
    struct { float Cs[64][CS_LD]; u16 Sw[64][SW_LD]; } e;      // 50 KiB
};

__global__ __launch_bounds__(256) void k_convF(
    const float* __restrict__ xin, const u16* __restrict__ wfxT,
    const float* __restrict__ bfx, const u16* __restrict__ swb,
    float* __restrict__ straw)
{
    __shared__ SmemCF sm;
    int pt = blockIdx.x;             // 0..255 = b*32 + ygroup
    int b = pt >> 5, yg = pt & 31;
    int ct = blockIdx.y;             // heads 2ct, 2ct+1
    int cob = ct << 7;
    int t = threadIdx.x;
    int lane = t & 63, wave = t >> 6;
    int wr = wave >> 1, wc = wave & 1;
    int l16 = lane & 15, lk = lane >> 4;
    int tg = t & 15, tc = t >> 4;

    float bb[4];
#pragma unroll
    for (int nj = 0; nj < 4; nj++) bb[nj] = bfx[cob + wc * 64 + nj * 16 + l16];

    float pacc[2][4][4];
#pragma unroll
    for (int h = 0; h < 2; h++)
#pragma unroll
        for (int i = 0; i < 4; i++)
#pragma unroll
            for (int j = 0; j < 4; j++) pacc[h][i][j] = 0.f;

    for (int r = 0; r < 4; r++) {
        int y = yg * 4 + r;
        v4f acc[4][4];
#pragma unroll
        for (int i = 0; i < 4; i++)
#pragma unroll
            for (int j = 0; j < 4; j++) acc[i][j] = v4f{0.f, 0.f, 0.f, 0.f};

        conv_core(xin, wfxT, sm.c.A, sm.c.B, b, y, cob, t, acc);
        __syncthreads();   // conv done; e.Cs/e.Sw alias A/B

        for (int s2 = 0; s2 < 2; s2++) {
            if (wr == s2) {
#pragma unroll
                for (int mi = 0; mi < 4; mi++)
#pragma unroll
                    for (int nj = 0; nj < 4; nj++)
#pragma unroll
                        for (int q = 0; q < 4; q++)
                            sm.e.Cs[mi * 16 + lk * 4 + q][wc * 64 + nj * 16 + l16] =
                                acc[mi][nj][q] + bb[nj];
            }
#pragma unroll
            for (int it = 0; it < 4; it++) {
                int q = it * 256 + t;         // 0..1023
                int hv = q >> 9, qq = q & 511;
                int p = qq >> 3, gq = (qq & 7) * 8;
                size_t idx = (((size_t)(b * HEADS + 2 * ct + hv) * NPIX) + (size_t)yg * 512 + r * 128 + s2 * 64 + p) * GS + gq;
                *(uint4*)&sm.e.Sw[p][hv * 64 + gq] = *(const uint4*)&swb[idx];
            }
            __syncthreads();
            for (int p = 0; p < 64; p++) {
#pragma unroll
                for (int h = 0; h < 2; h++) {
                    US4 w4 = *(const US4*)&sm.e.Sw[p][h * 64 + tg * 4];
                    float4 cv = *(const float4*)&sm.e.Cs[p][h * 64 + tc * 4];
                    float wv[4] = {bf2f(w4.x), bf2f(w4.y), bf2f(w4.z), bf2f(w4.w)};
                    float cc[4] = {cv.x, cv.y, cv.z, cv.w};
#pragma unroll
                    for (int i = 0; i < 4; i++)
#pragma unroll
                        for (int j = 0; j < 4; j++)
                            pacc[h][i][j] = fmaf(wv[i], cc[j], pacc[h][i][j]);
                }
            }
            __syncthreads();
        }
    }
#pragma unroll
    for (int h = 0; h < 2; h++)
#pragma unroll
        for (int i = 0; i < 4; i++)
#pragma unroll
            for (int j = 0; j < 4; j++)
                atomicAdd(&straw[((size_t)(b * HEADS + 2 * ct + h) * 64 + tg * 4 + i) * 64 + tc * 4 + j],
                          pacc[h][i][j]);
}

// ---------------------------------------------------------------------------
// K4: per-(b,h): normalize slice_token, q/k/v, 64x64 attention, out_slice,
// fold out_w -> M1[bh][g][128]. One block per bh; 64 KiB LDS. (unchanged)
// ---------------------------------------------------------------------------
__global__ __launch_bounds__(256) void k_attn(
    const float* __restrict__ straw, const float* __restrict__ norm,
    const float* __restrict__ wq, const float* __restrict__ wk, const float* __restrict__ wv,
    const float* __restrict__ outw, float* __restrict__ m1)
{
    __shared__ float lds[4][64][64];
    int bh = blockIdx.x, h = bh & 7;
    int t = threadIdx.x;
    for (int i = t; i < 4096; i += 256) {
        int g = i >> 6;
        lds[0][g][i & 63] = straw[(size_t)bh * 4096 + i] / (norm[bh * 64 + g] + 1e-5f);
    }
    __syncthreads();
    int g = t >> 2, d0 = (t & 3) << 4;
    for (int d = d0; d < d0 + 16; d++) {
        float sq = 0.f, sk = 0.f, sv = 0.f;
        for (int c = 0; c < 64; c++) {
            float sc = lds[0][g][c];
            sq = fmaf(sc, wq[d * 64 + c], sq);
            sk = fmaf(sc, wk[d * 64 + c], sk);
            sv = fmaf(sc, wv[d * 64 + c], sv);
        }
        lds[1][g][d] = sq; lds[2][g][d] = sk; lds[3][g][d] = sv;
    }
    __syncthreads();
    float attnrow[16];
    for (int k2 = d0, i = 0; k2 < d0 + 16; k2++, i++) {
        float s = 0.f;
        for (int d = 0; d < 64; d++) s = fmaf(lds[1][g][d], lds[2][k2][d], s);
        attnrow[i] = s * 0.125f;
    }
    __syncthreads();
    for (int i = 0; i < 16; i++) lds[0][g][d0 + i] = attnrow[i];
    __syncthreads();
    if (t < 64) {
        float mx = -1e30f;
        for (int j = 0; j < 64; j++) mx = fmaxf(mx, lds[0][t][j]);
        float s = 0.f;
        for (int j = 0; j < 64; j++) { float e = __expf(lds[0][t][j] - mx); lds[0][t][j] = e; s += e; }
        float inv = 1.f / s;
        for (int j = 0; j < 64; j++) lds[0][t][j] *= inv;
    }
    __syncthreads();
    float osrow[16];
    for (int d = d0, i = 0; d < d0 + 16; d++, i++) {
        float s = 0.f;
        for (int kx = 0; kx < 64; kx++) s = fmaf(lds[0][g][kx], lds[3][kx][d], s);
        osrow[i] = s;
    }
    __syncthreads();
    for (int i = 0; i < 16; i++) lds[2][g][d0 + i] = osrow[i];
    __syncthreads();
    int dimb = (t & 3) << 5;
    for (int dim = dimb; dim < dimb + 32; dim++) {
        float s = 0.f;
        for (int c = 0; c < 64; c++)
            s = fmaf(lds[2][g][c], outw[(size_t)dim * INNER + h * 64 + c], s);
        m1[((size_t)bh * 64 + g) * DIMC + dim] = s;
    }
}

// ---------------------------------------------------------------------------
// K5: out[b][n][d] = sum_{h,g} sw[bh][n][g] * M1[bh][g][d] + out_b[d]. (unchanged)
// ---------------------------------------------------------------------------
__global__ __launch_bounds__(256) void k_final(
    const u16* __restrict__ swb, const float* __restrict__ m1,
    const float* __restrict__ outb, float* __restrict__ out)
{
    __shared__ float As[32][68];    // sw^T: [g][n]
    __shared__ float Bs[32][128];   // M1:   [g][d]
    int b = blockIdx.x, nt = blockIdx.y;
    int t = threadIdx.x;
    int tn = t & 15, tm = t >> 4;
    float acc[4][8];
#pragma unroll
    for (int i = 0; i < 4; i++)
#pragma unroll
        for (int j = 0; j < 8; j++) acc[i][j] = 0.f;
    int n0 = nt * 64;
    int nl = t >> 2, gq = (t & 3) * 8;
    int gg = t >> 3, dd = (t & 7) * 16;
    for (int h = 0; h < HEADS; h++) {
        const u16* swp = swb + ((size_t)(b * HEADS + h) * NPIX + n0) * 64;
        const float* m1p = m1 + (size_t)(b * HEADS + h) * GS * DIMC;
        for (int g0 = 0; g0 < 64; g0 += 32) {
            __syncthreads();
            BF8 av8; av8.v = *(const uint4*)&swp[(size_t)nl * 64 + g0 + gq];
#pragma unroll
            for (int i = 0; i < 8; i++) As[gq + i][nl] = bf2f(av8.s[i]);
            const float* bp = m1p + (size_t)(g0 + gg) * DIMC + dd;
            *(float4*)&Bs[gg][dd + 0]  = *(const float4*)(bp + 0);
            *(float4*)&Bs[gg][dd + 4]  = *(const float4*)(bp + 4);
            *(float4*)&Bs[gg][dd + 8]  = *(const float4*)(bp + 8);
            *(float4*)&Bs[gg][dd + 12] = *(const float4*)(bp + 12);
            __syncthreads();
#pragma unroll
            for (int kk = 0; kk < 32; kk++) {
                float4 a = *(const float4*)&As[kk][tm * 4];
                float4 b0 = *(const float4*)&Bs[kk][tn * 4];
                float4 b1 = *(const float4*)&Bs[kk][tn * 4 + 64];
                float av[4] = {a.x, a.y, a.z, a.w};
                float bv[8] = {b0.x, b0.y, b0.z, b0.w, b1.x, b1.y, b1.z, b1.w};
#pragma unroll
                for (int i = 0; i < 4; i++)
#pragma unroll
                    for (int j = 0; j < 8; j++)
                        acc[i][j] = fmaf(av[i], bv[j], acc[i][j]);
            }
        }
    }
    float4 bias0 = *(const float4*)&outb[tn * 4];
    float4 bias1 = *(const float4*)&outb[64 + tn * 4];
#pragma unroll
    for (int i = 0; i < 4; i++) {
        size_t n = (size_t)n0 + tm * 4 + i;
        size_t rb = ((size_t)b * NPIX + n) * DIMC;
        float4 r0, r1;
        r0.x = acc[i][0] + bias0.x; r0.y = acc[i][1] + bias0.y;
        r0.z = acc[i][2] + bias0.z; r0.w = acc[i][3] + bias0.w;
        r1.x = acc[i][4] + bias1.x; r1.y = acc[i][5] + bias1.y;
        r1.z = acc[i][6] + bias1.z; r1.w = acc[i][7] + bias1.w;
        *(float4*)&out[rb + tn * 4] = r0;
        *(float4*)&out[rb + 64 + tn * 4] = r1;
    }
}

// ---------------------------------------------------------------------------
extern "C" void kernel_launch(void* const* d_in, const int* in_sizes, int n_in,
                              void* d_out, int out_size, void* d_ws, size_t ws_size,
                              hipStream_t stream)
{
    (void)in_sizes; (void)n_in; (void)out_size;
    const float* x    = (const float*)d_in[0];
    const float* wfx  = (const float*)d_in[1];
    const float* bfx  = (const float*)d_in[2];
    const float* wx   = (const float*)d_in[3];
    const float* bx   = (const float*)d_in[4];
    const float* slw  = (const float*)d_in[5];
    const float* slb  = (const float*)d_in[6];
    const float* temp = (const float*)d_in[7];
    const float* wq   = (const float*)d_in[8];
    const float* wk   = (const float*)d_in[9];
    const float* wv   = (const float*)d_in[10];
    const float* outw = (const float*)d_in[11];
    const float* outb = (const float*)d_in[12];
    float* out = (float*)d_out;
    float* W = (float*)d_ws;

    // workspace layout (float offsets) — total identical to verified baseline
    u16*   wcatT = (u16*)W;               // 589,824 u16  (= 294,912 floats)
    u16*   wfxT  = (u16*)(W + 294912);    // 589,824 u16
    float* bcatL = W + 589824;            //       512
    float* norm  = W + 590336;            //     4,096   (zeroed)
    float* straw = W + 594432;            //   262,144   (zeroed, contiguous w/ norm)
    float* m1    = W + 856576;            //   524,288
    u16*   swb   = (u16*)(W + 1380864);   // 67,108,864 u16 = 128 MiB
    const size_t need = 1380864ull * 4 + 67108864ull * 2;   // 139,741,184 B
    if (ws_size < need) return;

    hipMemsetAsync(norm, 0, (4096 + 262144) * sizeof(float), stream);

    k_build_w<<<dim3(1152), 256, 0, stream>>>(wx, wfx, slw, temp, wcatT, wfxT);
    k_build_b<<<dim3(1), 512, 0, stream>>>(bx, slw, slb, temp, bcatL);
    k_convL<<<dim3(1024, 4), 256, 0, stream>>>(x, wcatT, bcatL, swb, norm);
    k_convF<<<dim3(256, 4), 256, 0, stream>>>(x, wfxT, bfx, swb, straw);
    k_attn<<<dim3(64), 256, 0, stream>>>(straw, norm, wq, wk, wv, outw, m1);
    k_final<<<dim3(8, 256), 256, 0, stream>>>(swb, m1, outb, out);
}

// Round 2
// 1641.802 us; speedup vs baseline: 1.2652x; 1.2652x over previous
//
#include <hip/hip_runtime.h>
#include <stdint.h>

#define BATCH 8
#define HEADS 8
#define HM 128
#define WM 128
#define NPIX (HM*WM)      // 16384
#define DIMC 128
#define DH 64
#define GS 64
#define INNER 512
#define KTOT 1152         // 9*128 folded conv K
#define CS_LD 132         // fp32 row pad: 528 B/row, 16B-aligned, 2-way banks
#define SW_LD 136         // u16 row pad: 272 B/row, 16B-aligned
#define X_LD 136          // bf16 x-row pad: 272 B/row -> 2-way banks on frag reads
#define B_LD 72           // bf16 B-tile pad: 144 B/row -> 2-way banks
#define BBUF (128 * B_LD)

typedef unsigned short u16;
typedef short v8s __attribute__((ext_vector_type(8)));   // 8 bf16 in 4 VGPRs
typedef float v4f __attribute__((ext_vector_type(4)));   // MFMA accum

__device__ __forceinline__ u16 f2bf(float f) {
    unsigned x = __float_as_uint(f);
    return (u16)((x + 0x7fffu + ((x >> 16) & 1u)) >> 16);   // RNE
}
__device__ __forceinline__ float bf2f(u16 u) { return __uint_as_float(((unsigned)u) << 16); }
__device__ __forceinline__ unsigned cvtpk(float lo, float hi) {   // HW RNE pack: {hi,lo}
    unsigned r;
    asm("v_cvt_pk_bf16_f32 %0, %1, %2" : "=v"(r) : "v"(lo), "v"(hi));
    return r;
}

struct alignas(8) US4 { u16 x, y, z, w; };
union BF8 { uint4 v; u16 s[8]; };

// ---------------------------------------------------------------------------
// Build folded logit weights, TRANSPOSED + bf16:
//   wcatT[co][k=s*128+ci] = (sum_c conv_x_w[k][h*64+c]*slice_w[g][c]) / clip(temp)
// Also emit wfxT[co][k] = bf16(conv_fx_w[k][co]).
// ---------------------------------------------------------------------------
__global__ __launch_bounds__(256) void k_build_w(
    const float* __restrict__ wx, const float* __restrict__ wfx,
    const float* __restrict__ slw, const float* __restrict__ temp,
    u16* __restrict__ wcatT, u16* __restrict__ wfxT)
{
    __shared__ float sw_l[GS][DH + 1];
    __shared__ float wx_l[INNER];
    int row = blockIdx.x;            // 0..1151
    int t = threadIdx.x;
    for (int i = t; i < GS * DH; i += 256) sw_l[i >> 6][i & 63] = slw[i];
    for (int i = t; i < INNER; i += 256) wx_l[i] = wx[(size_t)row * INNER + i];
    __syncthreads();
#pragma unroll
    for (int j = 0; j < 2; j++) {
        int co = j * 256 + t;
        int h = co >> 6, g = co & 63;
        float s = 0.f;
        for (int c = 0; c < DH; c++) s = fmaf(wx_l[h * 64 + c], sw_l[g][c], s);
        float tv = fminf(fmaxf(temp[h], 0.1f), 5.0f);
        wcatT[(size_t)co * KTOT + row] = f2bf(s / tv);
        wfxT[(size_t)co * KTOT + row] = f2bf(wfx[(size_t)row * INNER + co]);
    }
}

__global__ __launch_bounds__(512) void k_build_b(
    const float* __restrict__ bx, const float* __restrict__ slw,
    const float* __restrict__ slb, const float* __restrict__ temp,
    float* __restrict__ bcatL)
{
    int co = threadIdx.x;            // 0..511
    int h = co >> 6, g = co & 63;
    float s = slb[g];
    for (int c = 0; c < DH; c++) s = fmaf(bx[h * 64 + c], slw[g * 64 + c], s);
    float tv = fminf(fmaxf(temp[h], 0.1f), 5.0f);
    bcatL[co] = s / tv;
}

// ---------------------------------------------------------------------------
// MFMA conv core v2: per output row (128 px x 128 ch, K=1152):
//  - per ky: stage ONE zero-padded 130-px x-row (fp32 -> bf16 via v_cvt_pk),
//    reused by all 3 kx shifts (shifted LDS fragment reads).
//  - B staged per (tap, ci-half) chunk of K=64, double-buffered: staging of
//    chunk c+1 overlaps MFMA of chunk c; ONE barrier per chunk.
//  - 21 barriers/row (was 36), A-traffic/convert cut 6x.
// Fragment mapping identical to the harness-verified round-1 kernel.
// ---------------------------------------------------------------------------
__device__ __forceinline__ void stage_b_chunk(const u16* wrow, u16* bd, int s, int cih)
{
    const u16* wp = wrow + s * DIMC + cih * 64;
#pragma unroll
    for (int u = 0; u < 4; u++)
        *(uint4*)(bd + u * 8) = *(const uint4*)(wp + u * 8);
}

__device__ __forceinline__ void conv_core2(
    const float* __restrict__ xin, const u16* __restrict__ wT,
    u16* __restrict__ Xs, u16* __restrict__ Bs,
    int b, int y, int cob, int t, v4f acc[][4])
{
    int lane = t & 63;
    int l16 = lane & 15, lk = lane >> 4;
    int wave = t >> 6, wr = wave >> 1, wc = wave & 1;
    int brow = t >> 1, bhalf = t & 1;
    const u16* wrow = wT + (size_t)(cob + brow) * KTOT + bhalf * 32;
    u16* bd0 = Bs + brow * B_LD + bhalf * 32;

    int cur = 0;
    for (int ky = 0; ky < 3; ky++) {
        int yy = y + ky - 1;
        bool yok = (unsigned)yy < (unsigned)HM;
        const float* xrow = xin + ((size_t)b * NPIX + (size_t)yy * WM) * DIMC;
        // ---- stage X(ky): 130 rows (px -1..128) x 128 ci, zeros at edges ----
        for (int i = t; i < 520; i += 256) {
            int row = i >> 2, q = i & 3;
            int px = row - 1;
            uint4 o0, o1, o2, o3;
            if (yok && (unsigned)px < (unsigned)WM) {
                const float4* p = (const float4*)(xrow + (size_t)px * DIMC + q * 32);
                float4 f0 = p[0], f1 = p[1], f2 = p[2], f3 = p[3];
                float4 f4 = p[4], f5 = p[5], f6 = p[6], f7 = p[7];
                o0 = make_uint4(cvtpk(f0.x,f0.y), cvtpk(f0.z,f0.w), cvtpk(f1.x,f1.y), cvtpk(f1.z,f1.w));
                o1 = make_uint4(cvtpk(f2.x,f2.y), cvtpk(f2.z,f2.w), cvtpk(f3.x,f3.y), cvtpk(f3.z,f3.w));
                o2 = make_uint4(cvtpk(f4.x,f4.y), cvtpk(f4.z,f4.w), cvtpk(f5.x,f5.y), cvtpk(f5.z,f5.w));
                o3 = make_uint4(cvtpk(f6.x,f6.y), cvtpk(f6.z,f6.w), cvtpk(f7.x,f7.y), cvtpk(f7.z,f7.w));
            } else {
                o0 = o1 = o2 = o3 = make_uint4(0u, 0u, 0u, 0u);
            }
            u16* d = Xs + row * X_LD + q * 32;
            *(uint4*)(d + 0)  = o0;
            *(uint4*)(d + 8)  = o1;
            *(uint4*)(d + 16) = o2;
            *(uint4*)(d + 24) = o3;
        }
        // first B chunk of this ky into buf[cur]
        stage_b_chunk(wrow, bd0 + cur * BBUF, ky * 3, 0);
        __syncthreads();
#pragma unroll
        for (int c = 0; c < 6; c++) {
            if (c < 5)   // overlap: stage next chunk into the other buffer
                stage_b_chunk(wrow, bd0 + (cur ^ 1) * BBUF,
                              ky * 3 + ((c + 1) >> 1), (c + 1) & 1);
            int kx = c >> 1, cih = c & 1;
            const u16* bb = Bs + cur * BBUF + (wc * 64 + l16) * B_LD + lk * 8;
            const u16* xb = Xs + (wr * 64 + l16 + kx) * X_LD + cih * 64 + lk * 8;
#pragma unroll
            for (int ks = 0; ks < 2; ks++) {
                v8s av[4], bv[4];
#pragma unroll
                for (int mi = 0; mi < 4; mi++)
                    av[mi] = *(const v8s*)(xb + mi * 16 * X_LD + ks * 32);
#pragma unroll
                for (int nj = 0; nj < 4; nj++)
                    bv[nj] = *(const v8s*)(bb + nj * 16 * B_LD + ks * 32);
#pragma unroll
                for (int mi = 0; mi < 4; mi++)
#pragma unroll
                    for (int nj = 0; nj < 4; nj++)
                        acc[mi][nj] = __builtin_amdgcn_mfma_f32_16x16x32_bf16(
                            av[mi], bv[nj], acc[mi][nj], 0, 0, 0);
            }
            __syncthreads();
            if (c < 5) cur ^= 1;
        }
    }
}

// ---------------------------------------------------------------------------
// Pass L: MFMA conv -> 512 logit channels; fused per-pixel softmax per head;
// sw stored bf16; slice_norm via one atomic per (h,g) per block.
// ---------------------------------------------------------------------------
union SmemCL {
    struct { u16 X[130 * X_LD]; u16 B[2 * 128 * B_LD]; } c;   // 35,360 + 36,864 B
    float Cs[64][CS_LD];                                      // 33,792 B epilogue
};

__global__ __launch_bounds__(256) void k_convL(
    const float* __restrict__ xin, const u16* __restrict__ wcatT,
    const float* __restrict__ bcatL, u16* __restrict__ swb, float* __restrict__ norm)
{
    __shared__ SmemCL sm;
    int pt = blockIdx.x;             // 0..1023 = b*128 + y
    int b = pt >> 7, y = pt & 127;
    int ct = blockIdx.y;             // heads 2ct, 2ct+1
    int cob = ct << 7;
    int t = threadIdx.x;
    int lane = t & 63, wave = t >> 6;
    int wr = wave >> 1, wc = wave & 1;
    int l16 = lane & 15, lk = lane >> 4;

    v4f acc[4][4];
#pragma unroll
    for (int i = 0; i < 4; i++)
#pragma unroll
        for (int j = 0; j < 4; j++) acc[i][j] = v4f{0.f, 0.f, 0.f, 0.f};

    conv_core2(xin, wcatT, sm.c.X, sm.c.B, b, y, cob, t, acc);
    __syncthreads();   // conv done; Cs aliases X/B

    float bb[4];
#pragma unroll
    for (int nj = 0; nj < 4; nj++) bb[nj] = bcatL[cob + wc * 64 + nj * 16 + l16];

    float normacc = 0.f;
    for (int s2 = 0; s2 < 2; s2++) {          // pixel halves: waves wr==s2 own them
        if (wr == s2) {
#pragma unroll
            for (int mi = 0; mi < 4; mi++)
#pragma unroll
                for (int nj = 0; nj < 4; nj++)
#pragma unroll
                    for (int q = 0; q < 4; q++)
                        sm.Cs[mi * 16 + lk * 4 + q][wc * 64 + nj * 16 + l16] =
                            acc[mi][nj][q] + bb[nj];
        }
        __syncthreads();
        if (t < 128) {                        // one (pixel, head) softmax per thread
            int p = t & 63, h = t >> 6;
            float mx = -1e30f;
            for (int j = 0; j < 64; j++) mx = fmaxf(mx, sm.Cs[p][h * 64 + j]);
            float ssum = 0.f;
            for (int j = 0; j < 64; j++) {
                float e = __expf(sm.Cs[p][h * 64 + j] - mx);
                sm.Cs[p][h * 64 + j] = e; ssum += e;
            }
            float inv = 1.f / ssum;
            for (int j = 0; j < 64; j++) sm.Cs[p][h * 64 + j] *= inv;
        }
        __syncthreads();
        if (t < 128) {                        // column-reduce for slice_norm
            float sacc = 0.f;
            for (int p = 0; p < 64; p++) sacc += sm.Cs[p][t];
            normacc += sacc;
        }
#pragma unroll
        for (int it = 0; it < 8; it++) {      // coalesced bf16 store of sw
            int q = it * 256 + t;             // 0..2047
            int hv = q >> 10, qq = q & 1023;
            int p = qq >> 4, gq = (qq & 15) * 4;
            US4 r;
            r.x = f2bf(sm.Cs[p][hv * 64 + gq + 0]);
            r.y = f2bf(sm.Cs[p][hv * 64 + gq + 1]);
            r.z = f2bf(sm.Cs[p][hv * 64 + gq + 2]);
            r.w = f2bf(sm.Cs[p][hv * 64 + gq + 3]);
            size_t idx = (((size_t)(b * HEADS + 2 * ct + hv) * NPIX) + (size_t)y * WM + s2 * 64 + p) * GS + gq;
            *(US4*)&swb[idx] = r;
        }
        __syncthreads();
    }
    if (t < 128) {
        int h = t >> 6, g = t & 63;
        atomicAdd(&norm[(b * HEADS + 2 * ct + h) * GS + g], normacc);
    }
}

// ---------------------------------------------------------------------------
// Pass F: MFMA conv -> 512 fx channels; epilogue pools against sw (bf16)
// into slice_token partials. 4 y-rows per block to amortize straw atomics.
// ---------------------------------------------------------------------------
union SmemCF {
    struct { u16 X[130 * X_LD]; u16 B[2 * 128 * B_LD]; } c;       // 72,224 B
    struct { float Cs[64][CS_LD]; u16 Sw[64][SW_LD]; } e;         // 51,200 B
};

__global__ __launch_bounds__(256) void k_convF(
    const float* __restrict__ xin, const u16* __restrict__ wfxT,
    const float* __restrict__ bfx, const u16* __restrict__ swb,
    float* __restrict__ straw)
{
    __shared__ SmemCF sm;
    int pt = blockIdx.x;             // 0..255 = b*32 + ygroup
    int b = pt >> 5, yg = pt & 31;
    int ct = blockIdx.y;             // heads 2ct, 2ct+1
    int cob = ct << 7;
    int t = threadIdx.x;
    int lane = t & 63, wave = t >> 6;
    int wr = wave >> 1, wc = wave & 1;
    int l16 = lane & 15, lk = lane >> 4;
    int tg = t & 15, tc = t >> 4;

    float bb[4];
#pragma unroll
    for (int nj = 0; nj < 4; nj++) bb[nj] = bfx[cob + wc * 64 + nj * 16 + l16];

    float pacc[2][4][4];
#pragma unroll
    for (int h = 0; h < 2; h++)
#pragma unroll
        for (int i = 0; i < 4; i++)
#pragma unroll
            for (int j = 0; j < 4; j++) pacc[h][i][j] = 0.f;

    for (int r = 0; r < 4; r++) {
        int y = yg * 4 + r;
        v4f acc[4][4];
#pragma unroll
        for (int i = 0; i < 4; i++)
#pragma unroll
            for (int j = 0; j < 4; j++) acc[i][j] = v4f{0.f, 0.f, 0.f, 0.f};

        conv_core2(xin, wfxT, sm.c.X, sm.c.B, b, y, cob, t, acc);
        __syncthreads();   // conv done; e.Cs/e.Sw alias X/B

        for (int s2 = 0; s2 < 2; s2++) {
            if (wr == s2) {
#pragma unroll
                for (int mi = 0; mi < 4; mi++)
#pragma unroll
                    for (int nj = 0; nj < 4; nj++)
#pragma unroll
                        for (int q = 0; q < 4; q++)
                            sm.e.Cs[mi * 16 + lk * 4 + q][wc * 64 + nj * 16 + l16] =
                                acc[mi][nj][q] + bb[nj];
            }
#pragma unroll
            for (int it = 0; it < 4; it++) {
                int q = it * 256 + t;         // 0..1023
                int hv = q >> 9, qq = q & 511;
                int p = qq >> 3, gq = (qq & 7) * 8;
                size_t idx = (((size_t)(b * HEADS + 2 * ct + hv) * NPIX) + (size_t)yg * 512 + r * 128 + s2 * 64 + p) * GS + gq;
                *(uint4*)&sm.e.Sw[p][hv * 64 + gq] = *(const uint4*)&swb[idx];
            }
            __syncthreads();
            for (int p = 0; p < 64; p++) {
#pragma unroll
                for (int h = 0; h < 2; h++) {
                    US4 w4 = *(const US4*)&sm.e.Sw[p][h * 64 + tg * 4];
                    float4 cv = *(const float4*)&sm.e.Cs[p][h * 64 + tc * 4];
                    float wv[4] = {bf2f(w4.x), bf2f(w4.y), bf2f(w4.z), bf2f(w4.w)};
                    float cc[4] = {cv.x, cv.y, cv.z, cv.w};
#pragma unroll
                    for (int i = 0; i < 4; i++)
#pragma unroll
                        for (int j = 0; j < 4; j++)
                            pacc[h][i][j] = fmaf(wv[i], cc[j], pacc[h][i][j]);
                }
            }
            __syncthreads();
        }
    }
#pragma unroll
    for (int h = 0; h < 2; h++)
#pragma unroll
        for (int i = 0; i < 4; i++)
#pragma unroll
            for (int j = 0; j < 4; j++)
                atomicAdd(&straw[((size_t)(b * HEADS + 2 * ct + h) * 64 + tg * 4 + i) * 64 + tc * 4 + j],
                          pacc[h][i][j]);
}

// ---------------------------------------------------------------------------
// K4: per-(b,h): normalize slice_token, q/k/v, 64x64 attention, out_slice,
// fold out_w -> M1[bh][g][128]. One block per bh; 64 KiB LDS. (unchanged)
// ---------------------------------------------------------------------------
__global__ __launch_bounds__(256) void k_attn(
    const float* __restrict__ straw, const float* __restrict__ norm,
    const float* __restrict__ wq, const float* __restrict__ wk, const float* __restrict__ wv,
    const float* __restrict__ outw, float* __restrict__ m1)
{
    __shared__ float lds[4][64][64];
    int bh = blockIdx.x, h = bh & 7;
    int t = threadIdx.x;
    for (int i = t; i < 4096; i += 256) {
        int g = i >> 6;
        lds[0][g][i & 63] = straw[(size_t)bh * 4096 + i] / (norm[bh * 64 + g] + 1e-5f);
    }
    __syncthreads();
    int g = t >> 2, d0 = (t & 3) << 4;
    for (int d = d0; d < d0 + 16; d++) {
        float sq = 0.f, sk = 0.f, sv = 0.f;
        for (int c = 0; c < 64; c++) {
            float sc = lds[0][g][c];
            sq = fmaf(sc, wq[d * 64 + c], sq);
            sk = fmaf(sc, wk[d * 64 + c], sk);
            sv = fmaf(sc, wv[d * 64 + c], sv);
        }
        lds[1][g][d] = sq; lds[2][g][d] = sk; lds[3][g][d] = sv;
    }
    __syncthreads();
    float attnrow[16];
    for (int k2 = d0, i = 0; k2 < d0 + 16; k2++, i++) {
        float s = 0.f;
        for (int d = 0; d < 64; d++) s = fmaf(lds[1][g][d], lds[2][k2][d], s);
        attnrow[i] = s * 0.125f;
    }
    __syncthreads();
    for (int i = 0; i < 16; i++) lds[0][g][d0 + i] = attnrow[i];
    __syncthreads();
    if (t < 64) {
        float mx = -1e30f;
        for (int j = 0; j < 64; j++) mx = fmaxf(mx, lds[0][t][j]);
        float s = 0.f;
        for (int j = 0; j < 64; j++) { float e = __expf(lds[0][t][j] - mx); lds[0][t][j] = e; s += e; }
        float inv = 1.f / s;
        for (int j = 0; j < 64; j++) lds[0][t][j] *= inv;
    }
    __syncthreads();
    float osrow[16];
    for (int d = d0, i = 0; d < d0 + 16; d++, i++) {
        float s = 0.f;
        for (int kx = 0; kx < 64; kx++) s = fmaf(lds[0][g][kx], lds[3][kx][d], s);
        osrow[i] = s;
    }
    __syncthreads();
    for (int i = 0; i < 16; i++) lds[2][g][d0 + i] = osrow[i];
    __syncthreads();
    int dimb = (t & 3) << 5;
    for (int dim = dimb; dim < dimb + 32; dim++) {
        float s = 0.f;
        for (int c = 0; c < 64; c++)
            s = fmaf(lds[2][g][c], outw[(size_t)dim * INNER + h * 64 + c], s);
        m1[((size_t)bh * 64 + g) * DIMC + dim] = s;
    }
}

// ---------------------------------------------------------------------------
// K5: out[b][n][d] = sum_{h,g} sw[bh][n][g] * M1[bh][g][d] + out_b[d]. (unchanged)
// ---------------------------------------------------------------------------
__global__ __launch_bounds__(256) void k_final(
    const u16* __restrict__ swb, const float* __restrict__ m1,
    const float* __restrict__ outb, float* __restrict__ out)
{
    __shared__ float As[32][68];    // sw^T: [g][n]
    __shared__ float Bs[32][128];   // M1:   [g][d]
    int b = blockIdx.x, nt = blockIdx.y;
    int t = threadIdx.x;
    int tn = t & 15, tm = t >> 4;
    float acc[4][8];
#pragma unroll
    for (int i = 0; i < 4; i++)
#pragma unroll
        for (int j = 0; j < 8; j++) acc[i][j] = 0.f;
    int n0 = nt * 64;
    int nl = t >> 2, gq = (t & 3) * 8;
    int gg = t >> 3, dd = (t & 7) * 16;
    for (int h = 0; h < HEADS; h++) {
        const u16* swp = swb + ((size_t)(b * HEADS + h) * NPIX + n0) * 64;
        const float* m1p = m1 + (size_t)(b * HEADS + h) * GS * DIMC;
        for (int g0 = 0; g0 < 64; g0 += 32) {
            __syncthreads();
            BF8 av8; av8.v = *(const uint4*)&swp[(size_t)nl * 64 + g0 + gq];
#pragma unroll
            for (int i = 0; i < 8; i++) As[gq + i][nl] = bf2f(av8.s[i]);
            const float* bp = m1p + (size_t)(g0 + gg) * DIMC + dd;
            *(float4*)&Bs[gg][dd + 0]  = *(const float4*)(bp + 0);
            *(float4*)&Bs[gg][dd + 4]  = *(const float4*)(bp + 4);
            *(float4*)&Bs[gg][dd + 8]  = *(const float4*)(bp + 8);
            *(float4*)&Bs[gg][dd + 12] = *(const float4*)(bp + 12);
            __syncthreads();
#pragma unroll
            for (int kk = 0; kk < 32; kk++) {
                float4 a = *(const float4*)&As[kk][tm * 4];
                float4 b0 = *(const float4*)&Bs[kk][tn * 4];
                float4 b1 = *(const float4*)&Bs[kk][tn * 4 + 64];
                float av[4] = {a.x, a.y, a.z, a.w};
                float bv[8] = {b0.x, b0.y, b0.z, b0.w, b1.x, b1.y, b1.z, b1.w};
#pragma unroll
                for (int i = 0; i < 4; i++)
#pragma unroll
                    for (int j = 0; j < 8; j++)
                        acc[i][j] = fmaf(av[i], bv[j], acc[i][j]);
            }
        }
    }
    float4 bias0 = *(const float4*)&outb[tn * 4];
    float4 bias1 = *(const float4*)&outb[64 + tn * 4];
#pragma unroll
    for (int i = 0; i < 4; i++) {
        size_t n = (size_t)n0 + tm * 4 + i;
        size_t rb = ((size_t)b * NPIX + n) * DIMC;
        float4 r0, r1;
        r0.x = acc[i][0] + bias0.x; r0.y = acc[i][1] + bias0.y;
        r0.z = acc[i][2] + bias0.z; r0.w = acc[i][3] + bias0.w;
        r1.x = acc[i][4] + bias1.x; r1.y = acc[i][5] + bias1.y;
        r1.z = acc[i][6] + bias1.z; r1.w = acc[i][7] + bias1.w;
        *(float4*)&out[rb + tn * 4] = r0;
        *(float4*)&out[rb + 64 + tn * 4] = r1;
    }
}

// ---------------------------------------------------------------------------
extern "C" void kernel_launch(void* const* d_in, const int* in_sizes, int n_in,
                              void* d_out, int out_size, void* d_ws, size_t ws_size,
                              hipStream_t stream)
{
    (void)in_sizes; (void)n_in; (void)out_size;
    const float* x    = (const float*)d_in[0];
    const float* wfx  = (const float*)d_in[1];
    const float* bfx  = (const float*)d_in[2];
    const float* wx   = (const float*)d_in[3];
    const float* bx   = (const float*)d_in[4];
    const float* slw  = (const float*)d_in[5];
    const float* slb  = (const float*)d_in[6];
    const float* temp = (const float*)d_in[7];
    const float* wq   = (const float*)d_in[8];
    const float* wk   = (const float*)d_in[9];
    const float* wv   = (const float*)d_in[10];
    const float* outw = (const float*)d_in[11];
    const float* outb = (const float*)d_in[12];
    float* out = (float*)d_out;
    float* W = (float*)d_ws;

    // workspace layout (float offsets) — identical to verified round-1
    u16*   wcatT = (u16*)W;               // 589,824 u16
    u16*   wfxT  = (u16*)(W + 294912);    // 589,824 u16
    float* bcatL = W + 589824;            //       512
    float* norm  = W + 590336;            //     4,096   (zeroed)
    float* straw = W + 594432;            //   262,144   (zeroed, contiguous w/ norm)
    float* m1    = W + 856576;            //   524,288
    u16*   swb   = (u16*)(W + 1380864);   // 67,108,864 u16 = 128 MiB
    const size_t need = 1380864ull * 4 + 67108864ull * 2;   // 139,741,184 B
    if (ws_size < need) return;

    hipMemsetAsync(norm, 0, (4096 + 262144) * sizeof(float), stream);

    k_build_w<<<dim3(1152), 256, 0, stream>>>(wx, wfx, slw, temp, wcatT, wfxT);
    k_build_b<<<dim3(1), 512, 0, stream>>>(bx, slw, slb, temp, bcatL);
    k_convL<<<dim3(1024, 4), 256, 0, stream>>>(x, wcatT, bcatL, swb, norm);
    k_convF<<<dim3(256, 4), 256, 0, stream>>>(x, wfxT, bfx, swb, straw);
    k_attn<<<dim3(64), 256, 0, stream>>>(straw, norm, wq, wk, wv, outw, m1);
    k_final<<<dim3(8, 256), 256, 0, stream>>>(swb, m1, outb, out);
}

// Round 3
// 1349.699 us; speedup vs baseline: 1.5390x; 1.2164x over previous
//
#include <hip/hip_runtime.h>
#include <stdint.h>

#define BATCH 8
#define HEADS 8
#define HM 128
#define WM 128
#define NPIX (HM*WM)      // 16384
#define DIMC 128
#define DH 64
#define GS 64
#define INNER 512
#define KTOT 1152         // 9*128 folded conv K
#define XT_LD 136         // bf16 X row: 128 data + 8 pad (272 B)
#define PT_LD 136         // bf16 SwT/FxT row: 128 data + 8 pad

typedef unsigned short u16;
typedef short v8s __attribute__((ext_vector_type(8)));   // 8 bf16 in 4 VGPRs
typedef float v4f __attribute__((ext_vector_type(4)));   // MFMA accum

__device__ __forceinline__ u16 f2bf(float f) {
    unsigned x = __float_as_uint(f);
    return (u16)((x + 0x7fffu + ((x >> 16) & 1u)) >> 16);   // RNE
}
__device__ __forceinline__ float bf2f(u16 u) { return __uint_as_float(((unsigned)u) << 16); }
__device__ __forceinline__ unsigned cvtpk(float lo, float hi) {   // HW RNE pack: {hi,lo}
    unsigned r;
    asm("v_cvt_pk_bf16_f32 %0, %1, %2" : "=v"(r) : "v"(lo), "v"(hi));
    return r;
}

union BF8 { uint4 v; u16 s[8]; };

// ---------------------------------------------------------------------------
// Build folded logit weights, TRANSPOSED + bf16:
//   wcatT[co][k=s*128+ci] = (sum_c conv_x_w[k][h*64+c]*slice_w[g][c]) / clip(temp)
// Also emit wfxT[co][k] = bf16(conv_fx_w[k][co]).
// ---------------------------------------------------------------------------
__global__ __launch_bounds__(256) void k_build_w(
    const float* __restrict__ wx, const float* __restrict__ wfx,
    const float* __restrict__ slw, const float* __restrict__ temp,
    u16* __restrict__ wcatT, u16* __restrict__ wfxT)
{
    __shared__ float sw_l[GS][DH + 1];
    __shared__ float wx_l[INNER];
    int row = blockIdx.x;            // 0..1151
    int t = threadIdx.x;
    for (int i = t; i < GS * DH; i += 256) sw_l[i >> 6][i & 63] = slw[i];
    for (int i = t; i < INNER; i += 256) wx_l[i] = wx[(size_t)row * INNER + i];
    __syncthreads();
#pragma unroll
    for (int j = 0; j < 2; j++) {
        int co = j * 256 + t;
        int h = co >> 6, g = co & 63;
        float s = 0.f;
        for (int c = 0; c < DH; c++) s = fmaf(wx_l[h * 64 + c], sw_l[g][c], s);
        float tv = fminf(fmaxf(temp[h], 0.1f), 5.0f);
        wcatT[(size_t)co * KTOT + row] = f2bf(s / tv);
        wfxT[(size_t)co * KTOT + row] = f2bf(wfx[(size_t)row * INNER + co]);
    }
}

__global__ __launch_bounds__(512) void k_build_b(
    const float* __restrict__ bx, const float* __restrict__ slw,
    const float* __restrict__ slb, const float* __restrict__ temp,
    float* __restrict__ bcatL)
{
    int co = threadIdx.x;            // 0..511
    int h = co >> 6, g = co & 63;
    float s = slb[g];
    for (int c = 0; c < DH; c++) s = fmaf(bx[h * 64 + c], slw[g * 64 + c], s);
    float tv = fminf(fmaxf(temp[h], 0.1f), 5.0f);
    bcatL[co] = s / tv;
}

// ---------------------------------------------------------------------------
// Fused conv kernel: per block = (b, y-row) x head-pair ct.
//  Phase 1: both 3x3 convs (logits + fx) as MFMA, K = 9 taps x 128 ci.
//    - X staged ONCE per ky (zero-padded 130 px), bf16 via v_cvt_pk,
//      XOR-swizzled (k8 ^= row&7) so fragment reads are ~2-way not 8-way.
//    - B fragments loaded per-lane DIRECTLY from global (L2-resident
//      weights), immediate offsets off 8 loop-invariant base pointers.
//      No B LDS, no B barriers: 2 barriers per ky.
//  Phase 2 (registers): bias + per-pixel softmax over 64 g via shfl_xor
//      within l16 groups; slice_norm via lk-reduce + 4 atomics/wave.
//  Phase 3: scatter sw -> SwT[g][p], fx -> FxT[ch][p] (bf16, swizzled);
//      pooling = MFMA over K=128 px: pacc[g][dh] += SwT x FxT.
//      swbT[bh][g][n] stored straight from SwT rows (coalesced 16B).
// ---------------------------------------------------------------------------
union SmemC {
    u16 X[130 * XT_LD];                                       // 35,360 B
    struct { u16 SwT[128][PT_LD]; u16 FxT[128][PT_LD]; } e;   // 69,632 B
};

__global__ __launch_bounds__(256) void k_conv2(
    const float* __restrict__ xin, const u16* __restrict__ wcatT,
    const u16* __restrict__ wfxT, const float* __restrict__ bcatL,
    const float* __restrict__ bfx, u16* __restrict__ swbT,
    float* __restrict__ straw, float* __restrict__ norm)
{
    __shared__ SmemC sm;
    int pt = blockIdx.x;             // 0..1023 = b*128 + y
    int b = pt >> 7, y = pt & 127;
    int ct = blockIdx.y;             // heads 2ct, 2ct+1
    int cob = ct << 7;
    int t = threadIdx.x;
    int lane = t & 63, wave = t >> 6;
    int wr = wave >> 1, wc = wave & 1;
    int l16 = lane & 15, lk = lane >> 4;

    v4f accL[4][4], accF[4][4];
#pragma unroll
    for (int i = 0; i < 4; i++)
#pragma unroll
        for (int j = 0; j < 4; j++) {
            accL[i][j] = v4f{0.f, 0.f, 0.f, 0.f};
            accF[i][j] = v4f{0.f, 0.f, 0.f, 0.f};
        }

    // loop-invariant B fragment base pointers (per nj), lane-resolved
    const u16* wlb[4]; const u16* wfb[4];
#pragma unroll
    for (int nj = 0; nj < 4; nj++) {
        size_t roff = (size_t)(cob + wc * 64 + nj * 16 + l16) * KTOT + lk * 8;
        wlb[nj] = wcatT + roff;
        wfb[nj] = wfxT + roff;
    }

    for (int ky = 0; ky < 3; ky++) {
        int yy = y + ky - 1;
        bool yok = (unsigned)yy < (unsigned)HM;
        const float* xrow = xin + ((size_t)b * NPIX + (size_t)yy * WM) * DIMC;
        __syncthreads();             // previous ky's readers done
        for (int i = t; i < 520; i += 256) {      // 130 px-rows x 4 quarters
            int row = i >> 2, q = i & 3;
            int px = row - 1;
            uint4 o0, o1, o2, o3;
            if (yok && (unsigned)px < (unsigned)WM) {
                const float4* p = (const float4*)(xrow + (size_t)px * DIMC + q * 32);
                float4 f0 = p[0], f1 = p[1], f2 = p[2], f3 = p[3];
                float4 f4 = p[4], f5 = p[5], f6 = p[6], f7 = p[7];
                o0 = make_uint4(cvtpk(f0.x,f0.y), cvtpk(f0.z,f0.w), cvtpk(f1.x,f1.y), cvtpk(f1.z,f1.w));
                o1 = make_uint4(cvtpk(f2.x,f2.y), cvtpk(f2.z,f2.w), cvtpk(f3.x,f3.y), cvtpk(f3.z,f3.w));
                o2 = make_uint4(cvtpk(f4.x,f4.y), cvtpk(f4.z,f4.w), cvtpk(f5.x,f5.y), cvtpk(f5.z,f5.w));
                o3 = make_uint4(cvtpk(f6.x,f6.y), cvtpk(f6.z,f6.w), cvtpk(f7.x,f7.y), cvtpk(f7.z,f7.w));
            } else {
                o0 = o1 = o2 = o3 = make_uint4(0u, 0u, 0u, 0u);
            }
            int r7 = row & 7;
            u16* xd = sm.X + row * XT_LD;
            *(uint4*)(xd + (((q * 4 + 0) ^ r7) * 8)) = o0;
            *(uint4*)(xd + (((q * 4 + 1) ^ r7) * 8)) = o1;
            *(uint4*)(xd + (((q * 4 + 2) ^ r7) * 8)) = o2;
            *(uint4*)(xd + (((q * 4 + 3) ^ r7) * 8)) = o3;
        }
        __syncthreads();
#pragma unroll
        for (int kx = 0; kx < 3; kx++) {
            int s = ky * 3 + kx;
            int xr7 = (l16 + kx) & 7;
            const u16* xb = sm.X + (wr * 64 + l16 + kx) * XT_LD;
#pragma unroll
            for (int c4 = 0; c4 < 4; c4++) {
                int wo = s * 128 + c4 * 32;
                v8s av[4], bL[4], bF[4];
#pragma unroll
                for (int nj = 0; nj < 4; nj++) {
                    bL[nj] = *(const v8s*)(wlb[nj] + wo);
                    bF[nj] = *(const v8s*)(wfb[nj] + wo);
                }
                int xo = (((c4 * 4 + lk) ^ xr7) * 8);
#pragma unroll
                for (int mi = 0; mi < 4; mi++)
                    av[mi] = *(const v8s*)(xb + mi * 16 * XT_LD + xo);
#pragma unroll
                for (int mi = 0; mi < 4; mi++)
#pragma unroll
                    for (int nj = 0; nj < 4; nj++) {
                        accL[mi][nj] = __builtin_amdgcn_mfma_f32_16x16x32_bf16(
                            av[mi], bL[nj], accL[mi][nj], 0, 0, 0);
                        accF[mi][nj] = __builtin_amdgcn_mfma_f32_16x16x32_bf16(
                            av[mi], bF[nj], accF[mi][nj], 0, 0, 0);
                    }
            }
        }
    }
    __syncthreads();   // conv done; X dead, epilogue tiles alias

    float bbL[4], bbF[4];
#pragma unroll
    for (int nj = 0; nj < 4; nj++) {
        bbL[nj] = bcatL[cob + wc * 64 + nj * 16 + l16];
        bbF[nj] = bfx[cob + wc * 64 + nj * 16 + l16];
    }

    // ---- per-pixel softmax over 64 g, fully in registers ----
    // pixel = wr*64 + mi*16 + lk*4 + q; its 64 g's live in nj(4) x l16(16)
#pragma unroll
    for (int mi = 0; mi < 4; mi++) {
#pragma unroll
        for (int q = 0; q < 4; q++) {
            float m = accL[mi][0][q] + bbL[0];
#pragma unroll
            for (int nj = 1; nj < 4; nj++) m = fmaxf(m, accL[mi][nj][q] + bbL[nj]);
            m = fmaxf(m, __shfl_xor(m, 1));
            m = fmaxf(m, __shfl_xor(m, 2));
            m = fmaxf(m, __shfl_xor(m, 4));
            m = fmaxf(m, __shfl_xor(m, 8));
            float ssum = 0.f;
#pragma unroll
            for (int nj = 0; nj < 4; nj++) {
                float e = __expf(accL[mi][nj][q] + bbL[nj] - m);
                accL[mi][nj][q] = e; ssum += e;
            }
            ssum += __shfl_xor(ssum, 1);
            ssum += __shfl_xor(ssum, 2);
            ssum += __shfl_xor(ssum, 4);
            ssum += __shfl_xor(ssum, 8);
            float inv = 1.f / ssum;
#pragma unroll
            for (int nj = 0; nj < 4; nj++) accL[mi][nj][q] *= inv;
        }
    }

    // ---- slice_norm: reduce over this wave's 64 pixels, 4 atomics/wave ----
#pragma unroll
    for (int nj = 0; nj < 4; nj++) {
        float pn = 0.f;
#pragma unroll
        for (int mi = 0; mi < 4; mi++)
#pragma unroll
            for (int q = 0; q < 4; q++) pn += accL[mi][nj][q];
        pn += __shfl_xor(pn, 16);
        pn += __shfl_xor(pn, 32);
        if (lk == 0)
            atomicAdd(&norm[(size_t)(b * HEADS + 2 * ct + wc) * GS + nj * 16 + l16], pn);
    }

    // ---- scatter sw -> SwT[g][p], fx -> FxT[ch][p] (bf16, swizzled) ----
    // p = wr*64 + mi*16 + lk*4 + q;  p8 = wr*8 + mi*2 + (lk>>1);  sub = (lk&1)*4
#pragma unroll
    for (int nj = 0; nj < 4; nj++) {
        int grow = wc * 64 + nj * 16 + l16;
        int r7 = l16 & 7;
#pragma unroll
        for (int mi = 0; mi < 4; mi++) {
            int off = (((wr * 8 + mi * 2 + (lk >> 1)) ^ r7) * 8) + (lk & 1) * 4;
            uint2 wv;
            wv.x = cvtpk(accL[mi][nj][0], accL[mi][nj][1]);
            wv.y = cvtpk(accL[mi][nj][2], accL[mi][nj][3]);
            *(uint2*)&sm.e.SwT[grow][off] = wv;
            uint2 fv;
            fv.x = cvtpk(accF[mi][nj][0] + bbF[nj], accF[mi][nj][1] + bbF[nj]);
            fv.y = cvtpk(accF[mi][nj][2] + bbF[nj], accF[mi][nj][3] + bbF[nj]);
            *(uint2*)&sm.e.FxT[grow][off] = fv;
        }
    }
    __syncthreads();

    // ---- pooling MFMA: pacc[g][dh] += sum_p SwT[g][p] * FxT[dh][p] ----
    // wave = (head wc, g-half wr): M=32 (mi 0..1), N=64 (nj 0..3), K=128 (c 0..3)
    v4f pacc[2][4];
#pragma unroll
    for (int i = 0; i < 2; i++)
#pragma unroll
        for (int j = 0; j < 4; j++) pacc[i][j] = v4f{0.f, 0.f, 0.f, 0.f};
    {
        int r7 = l16 & 7;
#pragma unroll
        for (int c = 0; c < 4; c++) {
            int ko = (((c * 4 + lk) ^ r7) * 8);
            v8s aw[2], bw[4];
#pragma unroll
            for (int mi = 0; mi < 2; mi++)
                aw[mi] = *(const v8s*)(&sm.e.SwT[wc * 64 + wr * 32 + mi * 16 + l16][0] + ko);
#pragma unroll
            for (int nj = 0; nj < 4; nj++)
                bw[nj] = *(const v8s*)(&sm.e.FxT[wc * 64 + nj * 16 + l16][0] + ko);
#pragma unroll
            for (int mi = 0; mi < 2; mi++)
#pragma unroll
                for (int nj = 0; nj < 4; nj++)
                    pacc[mi][nj] = __builtin_amdgcn_mfma_f32_16x16x32_bf16(
                        aw[mi], bw[nj], pacc[mi][nj], 0, 0, 0);
        }
    }

    // ---- swbT store: [bh][g][n], coalesced 16B chunks from SwT rows ----
#pragma unroll
    for (int it = 0; it < 8; it++) {
        int chunk = it * 256 + t;     // 0..2047
        int g = chunk >> 4;           // 0..127 (head = g>>6)
        int p8 = chunk & 15;
        uint4 v = *(const uint4*)(&sm.e.SwT[g][0] + ((p8 ^ (g & 7)) * 8));
        size_t di = (((size_t)(b * HEADS + 2 * ct + (g >> 6)) * GS + (g & 63)) * NPIX)
                    + (size_t)y * WM + p8 * 8;
        *(uint4*)&swbT[di] = v;
    }

    // ---- slice_token partials ----
    int bh = b * HEADS + 2 * ct + wc;
#pragma unroll
    for (int mi = 0; mi < 2; mi++)
#pragma unroll
        for (int nj = 0; nj < 4; nj++)
#pragma unroll
            for (int q = 0; q < 4; q++) {
                int g = wr * 32 + mi * 16 + lk * 4 + q;
                int dh = nj * 16 + l16;
                atomicAdd(&straw[((size_t)bh * GS + g) * DH + dh], pacc[mi][nj][q]);
            }
}

// ---------------------------------------------------------------------------
// K4: per-(b,h): normalize slice_token, q/k/v, 64x64 attention, out_slice,
// fold out_w -> M1[bh][g][128]. One block per bh; 64 KiB LDS. (unchanged)
// ---------------------------------------------------------------------------
__global__ __launch_bounds__(256) void k_attn(
    const float* __restrict__ straw, const float* __restrict__ norm,
    const float* __restrict__ wq, const float* __restrict__ wk, const float* __restrict__ wv,
    const float* __restrict__ outw, float* __restrict__ m1)
{
    __shared__ float lds[4][64][64];
    int bh = blockIdx.x, h = bh & 7;
    int t = threadIdx.x;
    for (int i = t; i < 4096; i += 256) {
        int g = i >> 6;
        lds[0][g][i & 63] = straw[(size_t)bh * 4096 + i] / (norm[bh * 64 + g] + 1e-5f);
    }
    __syncthreads();
    int g = t >> 2, d0 = (t & 3) << 4;
    for (int d = d0; d < d0 + 16; d++) {
        float sq = 0.f, sk = 0.f, sv = 0.f;
        for (int c = 0; c < 64; c++) {
            float sc = lds[0][g][c];
            sq = fmaf(sc, wq[d * 64 + c], sq);
            sk = fmaf(sc, wk[d * 64 + c], sk);
            sv = fmaf(sc, wv[d * 64 + c], sv);
        }
        lds[1][g][d] = sq; lds[2][g][d] = sk; lds[3][g][d] = sv;
    }
    __syncthreads();
    float attnrow[16];
    for (int k2 = d0, i = 0; k2 < d0 + 16; k2++, i++) {
        float s = 0.f;
        for (int d = 0; d < 64; d++) s = fmaf(lds[1][g][d], lds[2][k2][d], s);
        attnrow[i] = s * 0.125f;
    }
    __syncthreads();
    for (int i = 0; i < 16; i++) lds[0][g][d0 + i] = attnrow[i];
    __syncthreads();
    if (t < 64) {
        float mx = -1e30f;
        for (int j = 0; j < 64; j++) mx = fmaxf(mx, lds[0][t][j]);
        float s = 0.f;
        for (int j = 0; j < 64; j++) { float e = __expf(lds[0][t][j] - mx); lds[0][t][j] = e; s += e; }
        float inv = 1.f / s;
        for (int j = 0; j < 64; j++) lds[0][t][j] *= inv;
    }
    __syncthreads();
    float osrow[16];
    for (int d = d0, i = 0; d < d0 + 16; d++, i++) {
        float s = 0.f;
        for (int kx = 0; kx < 64; kx++) s = fmaf(lds[0][g][kx], lds[3][kx][d], s);
        osrow[i] = s;
    }
    __syncthreads();
    for (int i = 0; i < 16; i++) lds[2][g][d0 + i] = osrow[i];
    __syncthreads();
    int dimb = (t & 3) << 5;
    for (int dim = dimb; dim < dimb + 32; dim++) {
        float s = 0.f;
        for (int c = 0; c < 64; c++)
            s = fmaf(lds[2][g][c], outw[(size_t)dim * INNER + h * 64 + c], s);
        m1[((size_t)bh * 64 + g) * DIMC + dim] = s;
    }
}

// ---------------------------------------------------------------------------
// K5: out[b][n][d] = sum_{h,g} swT[bh][g][n] * M1[bh][g][d] + out_b[d].
// As fill reads transposed swbT rows directly (coalesced uint4).
// ---------------------------------------------------------------------------
__global__ __launch_bounds__(256) void k_final(
    const u16* __restrict__ swbT, const float* __restrict__ m1,
    const float* __restrict__ outb, float* __restrict__ out)
{
    __shared__ float As[32][68];    // sw^T: [g][n]
    __shared__ float Bs[32][128];   // M1:   [g][d]
    int b = blockIdx.x, nt = blockIdx.y;
    int t = threadIdx.x;
    int tn = t & 15, tm = t >> 4;
    float acc[4][8];
#pragma unroll
    for (int i = 0; i < 4; i++)
#pragma unroll
        for (int j = 0; j < 8; j++) acc[i][j] = 0.f;
    int n0 = nt * 64;
    int gg = t >> 3, nq = (t & 7) * 8;
    int g2 = t >> 3, dd = (t & 7) * 16;
    for (int h = 0; h < HEADS; h++) {
        const u16* swp = swbT + (size_t)(b * HEADS + h) * GS * NPIX;
        const float* m1p = m1 + (size_t)(b * HEADS + h) * GS * DIMC;
        for (int g0 = 0; g0 < 64; g0 += 32) {
            __syncthreads();
            BF8 av8; av8.v = *(const uint4*)&swp[(size_t)(g0 + gg) * NPIX + n0 + nq];
#pragma unroll
            for (int i = 0; i < 8; i++) As[gg][nq + i] = bf2f(av8.s[i]);
            const float* bp = m1p + (size_t)(g0 + g2) * DIMC + dd;
            *(float4*)&Bs[g2][dd + 0]  = *(const float4*)(bp + 0);
            *(float4*)&Bs[g2][dd + 4]  = *(const float4*)(bp + 4);
            *(float4*)&Bs[g2][dd + 8]  = *(const float4*)(bp + 8);
            *(float4*)&Bs[g2][dd + 12] = *(const float4*)(bp + 12);
            __syncthreads();
#pragma unroll
            for (int kk = 0; kk < 32; kk++) {
                float4 a = *(const float4*)&As[kk][tm * 4];
                float4 b0 = *(const float4*)&Bs[kk][tn * 4];
                float4 b1 = *(const float4*)&Bs[kk][tn * 4 + 64];
                float av[4] = {a.x, a.y, a.z, a.w};
                float bv[8] = {b0.x, b0.y, b0.z, b0.w, b1.x, b1.y, b1.z, b1.w};
#pragma unroll
                for (int i = 0; i < 4; i++)
#pragma unroll
                    for (int j = 0; j < 8; j++)
                        acc[i][j] = fmaf(av[i], bv[j], acc[i][j]);
            }
        }
    }
    float4 bias0 = *(const float4*)&outb[tn * 4];
    float4 bias1 = *(const float4*)&outb[64 + tn * 4];
#pragma unroll
    for (int i = 0; i < 4; i++) {
        size_t n = (size_t)n0 + tm * 4 + i;
        size_t rb = ((size_t)b * NPIX + n) * DIMC;
        float4 r0, r1;
        r0.x = acc[i][0] + bias0.x; r0.y = acc[i][1] + bias0.y;
        r0.z = acc[i][2] + bias0.z; r0.w = acc[i][3] + bias0.w;
        r1.x = acc[i][4] + bias1.x; r1.y = acc[i][5] + bias1.y;
        r1.z = acc[i][6] + bias1.z; r1.w = acc[i][7] + bias1.w;
        *(float4*)&out[rb + tn * 4] = r0;
        *(float4*)&out[rb + 64 + tn * 4] = r1;
    }
}

// ---------------------------------------------------------------------------
extern "C" void kernel_launch(void* const* d_in, const int* in_sizes, int n_in,
                              void* d_out, int out_size, void* d_ws, size_t ws_size,
                              hipStream_t stream)
{
    (void)in_sizes; (void)n_in; (void)out_size;
    const float* x    = (const float*)d_in[0];
    const float* wfx  = (const float*)d_in[1];
    const float* bfx  = (const float*)d_in[2];
    const float* wx   = (const float*)d_in[3];
    const float* bx   = (const float*)d_in[4];
    const float* slw  = (const float*)d_in[5];
    const float* slb  = (const float*)d_in[6];
    const float* temp = (const float*)d_in[7];
    const float* wq   = (const float*)d_in[8];
    const float* wk   = (const float*)d_in[9];
    const float* wv   = (const float*)d_in[10];
    const float* outw = (const float*)d_in[11];
    const float* outb = (const float*)d_in[12];
    float* out = (float*)d_out;
    float* W = (float*)d_ws;

    // workspace layout (float offsets) — identical footprint to verified round-2
    u16*   wcatT = (u16*)W;               // 589,824 u16
    u16*   wfxT  = (u16*)(W + 294912);    // 589,824 u16
    float* bcatL = W + 589824;            //       512
    float* norm  = W + 590336;            //     4,096   (zeroed)
    float* straw = W + 594432;            //   262,144   (zeroed, contiguous w/ norm)
    float* m1    = W + 856576;            //   524,288
    u16*   swbT  = (u16*)(W + 1380864);   // 67,108,864 u16 = 128 MiB, [bh][g][n]
    const size_t need = 1380864ull * 4 + 67108864ull * 2;   // 139,741,184 B
    if (ws_size < need) return;

    hipMemsetAsync(norm, 0, (4096 + 262144) * sizeof(float), stream);

    k_build_w<<<dim3(1152), 256, 0, stream>>>(wx, wfx, slw, temp, wcatT, wfxT);
    k_build_b<<<dim3(1), 512, 0, stream>>>(bx, slw, slb, temp, bcatL);
    k_conv2<<<dim3(1024, 4), 256, 0, stream>>>(x, wcatT, wfxT, bcatL, bfx, swbT, straw, norm);
    k_attn<<<dim3(64), 256, 0, stream>>>(straw, norm, wq, wk, wv, outw, m1);
    k_final<<<dim3(8, 256), 256, 0, stream>>>(swbT, m1, outb, out);
}

// Round 4
// 1311.987 us; speedup vs baseline: 1.5832x; 1.0287x over previous
//
#include <hip/hip_runtime.h>
#include <stdint.h>

#define BATCH 8
#define HEADS 8
#define HM 128
#define WM 128
#define NPIX (HM*WM)      // 16384
#define DIMC 128
#define DH 64
#define GS 64
#define INNER 512
#define KTOT 1152         // 9*128 folded conv K
#define XT_LD 128         // bf16 X row: NO pad; XOR swizzle supplies bank spread
#define PT_LD 128         // bf16 SwT/FxT row: NO pad; XOR swizzle

typedef unsigned short u16;
typedef short v8s __attribute__((ext_vector_type(8)));   // 8 bf16 in 4 VGPRs
typedef float v4f __attribute__((ext_vector_type(4)));   // MFMA accum

__device__ __forceinline__ u16 f2bf(float f) {
    unsigned x = __float_as_uint(f);
    return (u16)((x + 0x7fffu + ((x >> 16) & 1u)) >> 16);   // RNE
}
__device__ __forceinline__ float bf2f(u16 u) { return __uint_as_float(((unsigned)u) << 16); }
__device__ __forceinline__ unsigned cvtpk(float lo, float hi) {   // HW RNE pack: {hi,lo}
    unsigned r;
    asm("v_cvt_pk_bf16_f32 %0, %1, %2" : "=v"(r) : "v"(lo), "v"(hi));
    return r;
}

union BF8 { uint4 v; u16 s[8]; };

// ---------------------------------------------------------------------------
// Build folded logit weights, TRANSPOSED + bf16 (unchanged, verified).
// ---------------------------------------------------------------------------
__global__ __launch_bounds__(256) void k_build_w(
    const float* __restrict__ wx, const float* __restrict__ wfx,
    const float* __restrict__ slw, const float* __restrict__ temp,
    u16* __restrict__ wcatT, u16* __restrict__ wfxT)
{
    __shared__ float sw_l[GS][DH + 1];
    __shared__ float wx_l[INNER];
    int row = blockIdx.x;            // 0..1151
    int t = threadIdx.x;
    for (int i = t; i < GS * DH; i += 256) sw_l[i >> 6][i & 63] = slw[i];
    for (int i = t; i < INNER; i += 256) wx_l[i] = wx[(size_t)row * INNER + i];
    __syncthreads();
#pragma unroll
    for (int j = 0; j < 2; j++) {
        int co = j * 256 + t;
        int h = co >> 6, g = co & 63;
        float s = 0.f;
        for (int c = 0; c < DH; c++) s = fmaf(wx_l[h * 64 + c], sw_l[g][c], s);
        float tv = fminf(fmaxf(temp[h], 0.1f), 5.0f);
        wcatT[(size_t)co * KTOT + row] = f2bf(s / tv);
        wfxT[(size_t)co * KTOT + row] = f2bf(wfx[(size_t)row * INNER + co]);
    }
}

__global__ __launch_bounds__(512) void k_build_b(
    const float* __restrict__ bx, const float* __restrict__ slw,
    const float* __restrict__ slb, const float* __restrict__ temp,
    float* __restrict__ bcatL)
{
    int co = threadIdx.x;            // 0..511
    int h = co >> 6, g = co & 63;
    float s = slb[g];
    for (int c = 0; c < DH; c++) s = fmaf(bx[h * 64 + c], slw[g * 64 + c], s);
    float tv = fminf(fmaxf(temp[h], 0.1f), 5.0f);
    bcatL[co] = s / tv;
}

// ---------------------------------------------------------------------------
// Fused conv kernel v3:
//  - X staged per ky: slot-linear (lane = one 16B slot), XOR-swizzled into
//    XT_LD=128 rows (stride == 0 mod 32 dwords -> swizzle is conflict-free
//    on BOTH the staging writes and the fragment reads).
//  - B fragments: direct-from-global per lane, REGISTER DOUBLE-BUFFERED over
//    a flattened 36-chunk (tap x ci-quarter) loop: chunk c+1's 8 loads issue
//    before chunk c's 32 MFMAs, crossing kx/ky boundaries. No barriers inside
//    the chunk loop; 2 barriers per ky for X staging only.
//  - Epilogue (softmax-in-regs, pooling MFMA, swbT store) identical to the
//    verified round-3 kernel, with PT_LD=128.
// ---------------------------------------------------------------------------
union SmemC {
    u16 X[130 * XT_LD];                                       // 33,280 B
    struct { u16 SwT[128][PT_LD]; u16 FxT[128][PT_LD]; } e;   // 65,536 B
};

__global__ __launch_bounds__(256) void k_conv2(
    const float* __restrict__ xin, const u16* __restrict__ wcatT,
    const u16* __restrict__ wfxT, const float* __restrict__ bcatL,
    const float* __restrict__ bfx, u16* __restrict__ swbT,
    float* __restrict__ straw, float* __restrict__ norm)
{
    __shared__ SmemC sm;
    int pt = blockIdx.x;             // 0..1023 = b*128 + y
    int b = pt >> 7, y = pt & 127;
    int ct = blockIdx.y;             // heads 2ct, 2ct+1
    int cob = ct << 7;
    int t = threadIdx.x;
    int lane = t & 63, wave = t >> 6;
    int wr = wave >> 1, wc = wave & 1;
    int l16 = lane & 15, lk = lane >> 4;

    v4f accL[4][4], accF[4][4];
#pragma unroll
    for (int i = 0; i < 4; i++)
#pragma unroll
        for (int j = 0; j < 4; j++) {
            accL[i][j] = v4f{0.f, 0.f, 0.f, 0.f};
            accF[i][j] = v4f{0.f, 0.f, 0.f, 0.f};
        }

    // lane-resolved B row base pointers (per nj)
    const u16* wlb[4]; const u16* wfb[4];
#pragma unroll
    for (int nj = 0; nj < 4; nj++) {
        size_t roff = (size_t)(cob + wc * 64 + nj * 16 + l16) * KTOT + lk * 8;
        wlb[nj] = wcatT + roff;
        wfb[nj] = wfxT + roff;
    }

    // register double-buffer for B fragments
    v8s bL[2][4], bF[2][4];
    {   // prefetch global chunk 0 (wo = 0)
#pragma unroll
        for (int nj = 0; nj < 4; nj++) {
            bL[0][nj] = *(const v8s*)(wlb[nj]);
            bF[0][nj] = *(const v8s*)(wfb[nj]);
        }
    }

    for (int ky = 0; ky < 3; ky++) {
        int yy = y + ky - 1;
        bool yok = (unsigned)yy < (unsigned)HM;
        const float* xrow = xin + ((size_t)b * NPIX + (size_t)yy * WM) * DIMC;
        if (ky) __syncthreads();     // previous ky's fragment readers done
        // ---- stage X(ky): 130 rows x 16 slots of 16B, slot-linear ----
        for (int i = t; i < 2080; i += 256) {
            int row = i >> 4, k8 = i & 15;
            int px = row - 1;
            uint4 o;
            if (yok && (unsigned)px < (unsigned)WM) {
                const float4* p = (const float4*)(xrow + (size_t)px * DIMC + k8 * 8);
                float4 fa = p[0], fb = p[1];
                o = make_uint4(cvtpk(fa.x, fa.y), cvtpk(fa.z, fa.w),
                               cvtpk(fb.x, fb.y), cvtpk(fb.z, fb.w));
            } else {
                o = make_uint4(0u, 0u, 0u, 0u);
            }
            *(uint4*)(sm.X + row * XT_LD + ((k8 ^ (row & 7)) * 8)) = o;
        }
        __syncthreads();
        // ---- 12 chunks: prefetch B(c+1) then MFMA(c); no barriers ----
#pragma unroll
        for (int cc = 0; cc < 12; cc++) {
            int g = ky * 12 + cc;            // global chunk 0..35
            if (g < 35) {
                int wo = ((g + 1) >> 2) * 128 + ((g + 1) & 3) * 32;
#pragma unroll
                for (int nj = 0; nj < 4; nj++) {
                    bL[(cc + 1) & 1][nj] = *(const v8s*)(wlb[nj] + wo);
                    bF[(cc + 1) & 1][nj] = *(const v8s*)(wfb[nj] + wo);
                }
            }
            int kx = cc >> 2, c4 = cc & 3;
            int xr7 = (l16 + kx) & 7;
            const u16* xb = sm.X + (wr * 64 + l16 + kx) * XT_LD;
            int xo = (((c4 * 4 + lk) ^ xr7) * 8);
            v8s av[4];
#pragma unroll
            for (int mi = 0; mi < 4; mi++)
                av[mi] = *(const v8s*)(xb + mi * 16 * XT_LD + xo);
#pragma unroll
            for (int mi = 0; mi < 4; mi++)
#pragma unroll
                for (int nj = 0; nj < 4; nj++) {
                    accL[mi][nj] = __builtin_amdgcn_mfma_f32_16x16x32_bf16(
                        av[mi], bL[cc & 1][nj], accL[mi][nj], 0, 0, 0);
                    accF[mi][nj] = __builtin_amdgcn_mfma_f32_16x16x32_bf16(
                        av[mi], bF[cc & 1][nj], accF[mi][nj], 0, 0, 0);
                }
        }
    }
    __syncthreads();   // conv done; X dead, epilogue tiles alias

    float bbL[4], bbF[4];
#pragma unroll
    for (int nj = 0; nj < 4; nj++) {
        bbL[nj] = bcatL[cob + wc * 64 + nj * 16 + l16];
        bbF[nj] = bfx[cob + wc * 64 + nj * 16 + l16];
    }

    // ---- per-pixel softmax over 64 g, fully in registers ----
#pragma unroll
    for (int mi = 0; mi < 4; mi++) {
#pragma unroll
        for (int q = 0; q < 4; q++) {
            float m = accL[mi][0][q] + bbL[0];
#pragma unroll
            for (int nj = 1; nj < 4; nj++) m = fmaxf(m, accL[mi][nj][q] + bbL[nj]);
            m = fmaxf(m, __shfl_xor(m, 1));
            m = fmaxf(m, __shfl_xor(m, 2));
            m = fmaxf(m, __shfl_xor(m, 4));
            m = fmaxf(m, __shfl_xor(m, 8));
            float ssum = 0.f;
#pragma unroll
            for (int nj = 0; nj < 4; nj++) {
                float e = __expf(accL[mi][nj][q] + bbL[nj] - m);
                accL[mi][nj][q] = e; ssum += e;
            }
            ssum += __shfl_xor(ssum, 1);
            ssum += __shfl_xor(ssum, 2);
            ssum += __shfl_xor(ssum, 4);
            ssum += __shfl_xor(ssum, 8);
            float inv = 1.f / ssum;
#pragma unroll
            for (int nj = 0; nj < 4; nj++) accL[mi][nj][q] *= inv;
        }
    }

    // ---- slice_norm: reduce over this wave's 64 pixels, 4 atomics/wave ----
#pragma unroll
    for (int nj = 0; nj < 4; nj++) {
        float pn = 0.f;
#pragma unroll
        for (int mi = 0; mi < 4; mi++)
#pragma unroll
            for (int q = 0; q < 4; q++) pn += accL[mi][nj][q];
        pn += __shfl_xor(pn, 16);
        pn += __shfl_xor(pn, 32);
        if (lk == 0)
            atomicAdd(&norm[(size_t)(b * HEADS + 2 * ct + wc) * GS + nj * 16 + l16], pn);
    }

    // ---- scatter sw -> SwT[g][p], fx -> FxT[ch][p] (bf16, swizzled) ----
#pragma unroll
    for (int nj = 0; nj < 4; nj++) {
        int grow = wc * 64 + nj * 16 + l16;
        int r7 = l16 & 7;
#pragma unroll
        for (int mi = 0; mi < 4; mi++) {
            int off = (((wr * 8 + mi * 2 + (lk >> 1)) ^ r7) * 8) + (lk & 1) * 4;
            uint2 wv;
            wv.x = cvtpk(accL[mi][nj][0], accL[mi][nj][1]);
            wv.y = cvtpk(accL[mi][nj][2], accL[mi][nj][3]);
            *(uint2*)&sm.e.SwT[grow][off] = wv;
            uint2 fv;
            fv.x = cvtpk(accF[mi][nj][0] + bbF[nj], accF[mi][nj][1] + bbF[nj]);
            fv.y = cvtpk(accF[mi][nj][2] + bbF[nj], accF[mi][nj][3] + bbF[nj]);
            *(uint2*)&sm.e.FxT[grow][off] = fv;
        }
    }
    __syncthreads();

    // ---- pooling MFMA: pacc[g][dh] += sum_p SwT[g][p] * FxT[dh][p] ----
    v4f pacc[2][4];
#pragma unroll
    for (int i = 0; i < 2; i++)
#pragma unroll
        for (int j = 0; j < 4; j++) pacc[i][j] = v4f{0.f, 0.f, 0.f, 0.f};
    {
        int r7 = l16 & 7;
#pragma unroll
        for (int c = 0; c < 4; c++) {
            int ko = (((c * 4 + lk) ^ r7) * 8);
            v8s aw[2], bw[4];
#pragma unroll
            for (int mi = 0; mi < 2; mi++)
                aw[mi] = *(const v8s*)(&sm.e.SwT[wc * 64 + wr * 32 + mi * 16 + l16][0] + ko);
#pragma unroll
            for (int nj = 0; nj < 4; nj++)
                bw[nj] = *(const v8s*)(&sm.e.FxT[wc * 64 + nj * 16 + l16][0] + ko);
#pragma unroll
            for (int mi = 0; mi < 2; mi++)
#pragma unroll
                for (int nj = 0; nj < 4; nj++)
                    pacc[mi][nj] = __builtin_amdgcn_mfma_f32_16x16x32_bf16(
                        aw[mi], bw[nj], pacc[mi][nj], 0, 0, 0);
        }
    }

    // ---- swbT store: [bh][g][n], coalesced 16B chunks from SwT rows ----
#pragma unroll
    for (int it = 0; it < 8; it++) {
        int chunk = it * 256 + t;     // 0..2047
        int g = chunk >> 4;           // 0..127 (head = g>>6)
        int p8 = chunk & 15;
        uint4 v = *(const uint4*)(&sm.e.SwT[g][0] + ((p8 ^ (g & 7)) * 8));
        size_t di = (((size_t)(b * HEADS + 2 * ct + (g >> 6)) * GS + (g & 63)) * NPIX)
                    + (size_t)y * WM + p8 * 8;
        *(uint4*)&swbT[di] = v;
    }

    // ---- slice_token partials ----
    int bh = b * HEADS + 2 * ct + wc;
#pragma unroll
    for (int mi = 0; mi < 2; mi++)
#pragma unroll
        for (int nj = 0; nj < 4; nj++)
#pragma unroll
            for (int q = 0; q < 4; q++) {
                int g = wr * 32 + mi * 16 + lk * 4 + q;
                int dh = nj * 16 + l16;
                atomicAdd(&straw[((size_t)bh * GS + g) * DH + dh], pacc[mi][nj][q]);
            }
}

// ---------------------------------------------------------------------------
// K4: per-(b,h) attention -> M1 (unchanged, verified).
// ---------------------------------------------------------------------------
__global__ __launch_bounds__(256) void k_attn(
    const float* __restrict__ straw, const float* __restrict__ norm,
    const float* __restrict__ wq, const float* __restrict__ wk, const float* __restrict__ wv,
    const float* __restrict__ outw, float* __restrict__ m1)
{
    __shared__ float lds[4][64][64];
    int bh = blockIdx.x, h = bh & 7;
    int t = threadIdx.x;
    for (int i = t; i < 4096; i += 256) {
        int g = i >> 6;
        lds[0][g][i & 63] = straw[(size_t)bh * 4096 + i] / (norm[bh * 64 + g] + 1e-5f);
    }
    __syncthreads();
    int g = t >> 2, d0 = (t & 3) << 4;
    for (int d = d0; d < d0 + 16; d++) {
        float sq = 0.f, sk = 0.f, sv = 0.f;
        for (int c = 0; c < 64; c++) {
            float sc = lds[0][g][c];
            sq = fmaf(sc, wq[d * 64 + c], sq);
            sk = fmaf(sc, wk[d * 64 + c], sk);
            sv = fmaf(sc, wv[d * 64 + c], sv);
        }
        lds[1][g][d] = sq; lds[2][g][d] = sk; lds[3][g][d] = sv;
    }
    __syncthreads();
    float attnrow[16];
    for (int k2 = d0, i = 0; k2 < d0 + 16; k2++, i++) {
        float s = 0.f;
        for (int d = 0; d < 64; d++) s = fmaf(lds[1][g][d], lds[2][k2][d], s);
        attnrow[i] = s * 0.125f;
    }
    __syncthreads();
    for (int i = 0; i < 16; i++) lds[0][g][d0 + i] = attnrow[i];
    __syncthreads();
    if (t < 64) {
        float mx = -1e30f;
        for (int j = 0; j < 64; j++) mx = fmaxf(mx, lds[0][t][j]);
        float s = 0.f;
        for (int j = 0; j < 64; j++) { float e = __expf(lds[0][t][j] - mx); lds[0][t][j] = e; s += e; }
        float inv = 1.f / s;
        for (int j = 0; j < 64; j++) lds[0][t][j] *= inv;
    }
    __syncthreads();
    float osrow[16];
    for (int d = d0, i = 0; d < d0 + 16; d++, i++) {
        float s = 0.f;
        for (int kx = 0; kx < 64; kx++) s = fmaf(lds[0][g][kx], lds[3][kx][d], s);
        osrow[i] = s;
    }
    __syncthreads();
    for (int i = 0; i < 16; i++) lds[2][g][d0 + i] = osrow[i];
    __syncthreads();
    int dimb = (t & 3) << 5;
    for (int dim = dimb; dim < dimb + 32; dim++) {
        float s = 0.f;
        for (int c = 0; c < 64; c++)
            s = fmaf(lds[2][g][c], outw[(size_t)dim * INNER + h * 64 + c], s);
        m1[((size_t)bh * 64 + g) * DIMC + dim] = s;
    }
}

// ---------------------------------------------------------------------------
// K5: out[b][n][d] = sum_{h,g} swT[bh][g][n] * M1[bh][g][d] + out_b[d]
// (unchanged from verified round-3).
// ---------------------------------------------------------------------------
__global__ __launch_bounds__(256) void k_final(
    const u16* __restrict__ swbT, const float* __restrict__ m1,
    const float* __restrict__ outb, float* __restrict__ out)
{
    __shared__ float As[32][68];    // sw^T: [g][n]
    __shared__ float Bs[32][128];   // M1:   [g][d]
    int b = blockIdx.x, nt = blockIdx.y;
    int t = threadIdx.x;
    int tn = t & 15, tm = t >> 4;
    float acc[4][8];
#pragma unroll
    for (int i = 0; i < 4; i++)
#pragma unroll
        for (int j = 0; j < 8; j++) acc[i][j] = 0.f;
    int n0 = nt * 64;
    int gg = t >> 3, nq = (t & 7) * 8;
    int g2 = t >> 3, dd = (t & 7) * 16;
    for (int h = 0; h < HEADS; h++) {
        const u16* swp = swbT + (size_t)(b * HEADS + h) * GS * NPIX;
        const float* m1p = m1 + (size_t)(b * HEADS + h) * GS * DIMC;
        for (int g0 = 0; g0 < 64; g0 += 32) {
            __syncthreads();
            BF8 av8; av8.v = *(const uint4*)&swp[(size_t)(g0 + gg) * NPIX + n0 + nq];
#pragma unroll
            for (int i = 0; i < 8; i++) As[gg][nq + i] = bf2f(av8.s[i]);
            const float* bp = m1p + (size_t)(g0 + g2) * DIMC + dd;
            *(float4*)&Bs[g2][dd + 0]  = *(const float4*)(bp + 0);
            *(float4*)&Bs[g2][dd + 4]  = *(const float4*)(bp + 4);
            *(float4*)&Bs[g2][dd + 8]  = *(const float4*)(bp + 8);
            *(float4*)&Bs[g2][dd + 12] = *(const float4*)(bp + 12);
            __syncthreads();
#pragma unroll
            for (int kk = 0; kk < 32; kk++) {
                float4 a = *(const float4*)&As[kk][tm * 4];
                float4 b0 = *(const float4*)&Bs[kk][tn * 4];
                float4 b1 = *(const float4*)&Bs[kk][tn * 4 + 64];
                float av[4] = {a.x, a.y, a.z, a.w};
                float bv[8] = {b0.x, b0.y, b0.z, b0.w, b1.x, b1.y, b1.z, b1.w};
#pragma unroll
                for (int i = 0; i < 4; i++)
#pragma unroll
                    for (int j = 0; j < 8; j++)
                        acc[i][j] = fmaf(av[i], bv[j], acc[i][j]);
            }
        }
    }
    float4 bias0 = *(const float4*)&outb[tn * 4];
    float4 bias1 = *(const float4*)&outb[64 + tn * 4];
#pragma unroll
    for (int i = 0; i < 4; i++) {
        size_t n = (size_t)n0 + tm * 4 + i;
        size_t rb = ((size_t)b * NPIX + n) * DIMC;
        float4 r0, r1;
        r0.x = acc[i][0] + bias0.x; r0.y = acc[i][1] + bias0.y;
        r0.z = acc[i][2] + bias0.z; r0.w = acc[i][3] + bias0.w;
        r1.x = acc[i][4] + bias1.x; r1.y = acc[i][5] + bias1.y;
        r1.z = acc[i][6] + bias1.z; r1.w = acc[i][7] + bias1.w;
        *(float4*)&out[rb + tn * 4] = r0;
        *(float4*)&out[rb + 64 + tn * 4] = r1;
    }
}

// ---------------------------------------------------------------------------
extern "C" void kernel_launch(void* const* d_in, const int* in_sizes, int n_in,
                              void* d_out, int out_size, void* d_ws, size_t ws_size,
                              hipStream_t stream)
{
    (void)in_sizes; (void)n_in; (void)out_size;
    const float* x    = (const float*)d_in[0];
    const float* wfx  = (const float*)d_in[1];
    const float* bfx  = (const float*)d_in[2];
    const float* wx   = (const float*)d_in[3];
    const float* bx   = (const float*)d_in[4];
    const float* slw  = (const float*)d_in[5];
    const float* slb  = (const float*)d_in[6];
    const float* temp = (const float*)d_in[7];
    const float* wq   = (const float*)d_in[8];
    const float* wk   = (const float*)d_in[9];
    const float* wv   = (const float*)d_in[10];
    const float* outw = (const float*)d_in[11];
    const float* outb = (const float*)d_in[12];
    float* out = (float*)d_out;
    float* W = (float*)d_ws;

    // workspace layout (float offsets) — identical footprint to verified round-3
    u16*   wcatT = (u16*)W;               // 589,824 u16
    u16*   wfxT  = (u16*)(W + 294912);    // 589,824 u16
    float* bcatL = W + 589824;            //       512
    float* norm  = W + 590336;            //     4,096   (zeroed)
    float* straw = W + 594432;            //   262,144   (zeroed, contiguous w/ norm)
    float* m1    = W + 856576;            //   524,288
    u16*   swbT  = (u16*)(W + 1380864);   // 67,108,864 u16 = 128 MiB, [bh][g][n]
    const size_t need = 1380864ull * 4 + 67108864ull * 2;   // 139,741,184 B
    if (ws_size < need) return;

    hipMemsetAsync(norm, 0, (4096 + 262144) * sizeof(float), stream);

    k_build_w<<<dim3(1152), 256, 0, stream>>>(wx, wfx, slw, temp, wcatT, wfxT);
    k_build_b<<<dim3(1), 512, 0, stream>>>(bx, slw, slb, temp, bcatL);
    k_conv2<<<dim3(1024, 4), 256, 0, stream>>>(x, wcatT, wfxT, bcatL, bfx, swbT, straw, norm);
    k_attn<<<dim3(64), 256, 0, stream>>>(straw, norm, wq, wk, wv, outw, m1);
    k_final<<<dim3(8, 256), 256, 0, stream>>>(swbT, m1, outb, out);
}

// Round 5
// 1191.676 us; speedup vs baseline: 1.7431x; 1.1010x over previous
//
#include <hip/hip_runtime.h>
#include <stdint.h>

#define BATCH 8
#define HEADS 8
#define HM 128
#define WM 128
#define NPIX (HM*WM)      // 16384
#define DIMC 128
#define DH 64
#define GS 64
#define INNER 512
#define KTOT 1152         // 9*128 folded conv K
#define XT_LD 128         // bf16 X row: NO pad; XOR swizzle supplies bank spread
#define PT_LD 128         // bf16 SwT/FxT row: NO pad; XOR swizzle

typedef unsigned short u16;
typedef short v8s __attribute__((ext_vector_type(8)));   // 8 bf16 in 4 VGPRs
typedef float v4f __attribute__((ext_vector_type(4)));   // MFMA accum

__device__ __forceinline__ u16 f2bf(float f) {
    unsigned x = __float_as_uint(f);
    return (u16)((x + 0x7fffu + ((x >> 16) & 1u)) >> 16);   // RNE
}
__device__ __forceinline__ float bf2f(u16 u) { return __uint_as_float(((unsigned)u) << 16); }
__device__ __forceinline__ unsigned cvtpk(float lo, float hi) {   // HW RNE pack: {hi,lo}
    unsigned r;
    asm("v_cvt_pk_bf16_f32 %0, %1, %2" : "=v"(r) : "v"(lo), "v"(hi));
    return r;
}

union BF8 { uint4 v; u16 s[8]; };

// ---------------------------------------------------------------------------
// Build folded logit weights, TRANSPOSED + bf16 (unchanged, verified).
// ---------------------------------------------------------------------------
__global__ __launch_bounds__(256) void k_build_w(
    const float* __restrict__ wx, const float* __restrict__ wfx,
    const float* __restrict__ slw, const float* __restrict__ temp,
    u16* __restrict__ wcatT, u16* __restrict__ wfxT)
{
    __shared__ float sw_l[GS][DH + 1];
    __shared__ float wx_l[INNER];
    int row = blockIdx.x;            // 0..1151
    int t = threadIdx.x;
    for (int i = t; i < GS * DH; i += 256) sw_l[i >> 6][i & 63] = slw[i];
    for (int i = t; i < INNER; i += 256) wx_l[i] = wx[(size_t)row * INNER + i];
    __syncthreads();
#pragma unroll
    for (int j = 0; j < 2; j++) {
        int co = j * 256 + t;
        int h = co >> 6, g = co & 63;
        float s = 0.f;
        for (int c = 0; c < DH; c++) s = fmaf(wx_l[h * 64 + c], sw_l[g][c], s);
        float tv = fminf(fmaxf(temp[h], 0.1f), 5.0f);
        wcatT[(size_t)co * KTOT + row] = f2bf(s / tv);
        wfxT[(size_t)co * KTOT + row] = f2bf(wfx[(size_t)row * INNER + co]);
    }
}

__global__ __launch_bounds__(512) void k_build_b(
    const float* __restrict__ bx, const float* __restrict__ slw,
    const float* __restrict__ slb, const float* __restrict__ temp,
    float* __restrict__ bcatL)
{
    int co = threadIdx.x;            // 0..511
    int h = co >> 6, g = co & 63;
    float s = slb[g];
    for (int c = 0; c < DH; c++) s = fmaf(bx[h * 64 + c], slw[g * 64 + c], s);
    float tv = fminf(fmaxf(temp[h], 0.1f), 5.0f);
    bcatL[co] = s / tv;
}

// ---------------------------------------------------------------------------
// Fused conv kernel v4: 512 threads (8 waves), grid (1024, 2).
//  Block = (b, y-row) x 4-head group ct. Waves: w_half = px-half (2) x
//  w_co = head-within-group (4). Per-wave tile: 64 px x 64 co, both convs.
//  - X staged ONCE per (b,y,ky) serves all 8 waves (was 4x redundant).
//    Staging loop statically unrolled+predicated: all loads batch-issue.
//  - ky loop unrolled -> B chunk offsets are compile-time immediates.
//  - B fragments direct-from-global, register double-buffered, prefetch-1.
//  - Epilogue: verified softmax-in-regs; then 2 rounds (one head-pair each)
//    of the verified scatter/pool-MFMA/swbT-store code.
// ---------------------------------------------------------------------------
union SmemC {
    u16 X[130 * XT_LD];                                       // 33,280 B
    struct { u16 SwT[128][PT_LD]; u16 FxT[128][PT_LD]; } e;   // 65,536 B
};

__global__ __launch_bounds__(512) void k_conv2(
    const float* __restrict__ xin, const u16* __restrict__ wcatT,
    const u16* __restrict__ wfxT, const float* __restrict__ bcatL,
    const float* __restrict__ bfx, u16* __restrict__ swbT,
    float* __restrict__ straw, float* __restrict__ norm)
{
    __shared__ SmemC sm;
    int pt = blockIdx.x;             // 0..1023 = b*128 + y
    int b = pt >> 7, y = pt & 127;
    int ct = blockIdx.y;             // head group: heads 4ct..4ct+3
    int cob = ct << 8;               // 256 channels per block
    int t = threadIdx.x;
    int lane = t & 63, wave = t >> 6;
    int w_half = wave >> 2, w_co = wave & 3;
    int l16 = lane & 15, lk = lane >> 4;
    int hb = b * HEADS + 4 * ct;

    v4f accL[4][4], accF[4][4];
#pragma unroll
    for (int i = 0; i < 4; i++)
#pragma unroll
        for (int j = 0; j < 4; j++) {
            accL[i][j] = v4f{0.f, 0.f, 0.f, 0.f};
            accF[i][j] = v4f{0.f, 0.f, 0.f, 0.f};
        }

    // lane-resolved B row base pointers (per nj)
    const u16* wlb[4]; const u16* wfb[4];
#pragma unroll
    for (int nj = 0; nj < 4; nj++) {
        size_t roff = (size_t)(cob + w_co * 64 + nj * 16 + l16) * KTOT + lk * 8;
        wlb[nj] = wcatT + roff;
        wfb[nj] = wfxT + roff;
    }

    // register double-buffer for B fragments; prefetch chunk 0
    v8s bL[2][4], bF[2][4];
#pragma unroll
    for (int nj = 0; nj < 4; nj++) {
        bL[0][nj] = *(const v8s*)(wlb[nj]);
        bF[0][nj] = *(const v8s*)(wfb[nj]);
    }

#pragma unroll
    for (int ky = 0; ky < 3; ky++) {
        int yy = y + ky - 1;
        bool yok = (unsigned)yy < (unsigned)HM;
        const float* xrow = xin + ((size_t)b * NPIX + (size_t)yy * WM) * DIMC;
        if (ky) __syncthreads();     // previous ky's fragment readers done
        // ---- stage X(ky): 2080 slots of 16B; 5 predicated unrolled iters ----
#pragma unroll
        for (int it = 0; it < 5; it++) {
            int i = t + it * 512;
            if (i < 2080) {
                int row = i >> 4, k8 = i & 15;
                int px = row - 1;
                uint4 o;
                if (yok && (unsigned)px < (unsigned)WM) {
                    const float4* p = (const float4*)(xrow + (size_t)px * DIMC + k8 * 8);
                    float4 fa = p[0], fb = p[1];
                    o = make_uint4(cvtpk(fa.x, fa.y), cvtpk(fa.z, fa.w),
                                   cvtpk(fb.x, fb.y), cvtpk(fb.z, fb.w));
                } else {
                    o = make_uint4(0u, 0u, 0u, 0u);
                }
                *(uint4*)(sm.X + row * XT_LD + ((k8 ^ (row & 7)) * 8)) = o;
            }
        }
        __syncthreads();
        // ---- 12 chunks: prefetch B(c+1) (imm offsets) then MFMA(c) ----
#pragma unroll
        for (int cc = 0; cc < 12; cc++) {
            int g = ky * 12 + cc;            // compile-time after unroll
            if (g < 35) {
                int wo = ((g + 1) >> 2) * 128 + ((g + 1) & 3) * 32;
#pragma unroll
                for (int nj = 0; nj < 4; nj++) {
                    bL[(cc + 1) & 1][nj] = *(const v8s*)(wlb[nj] + wo);
                    bF[(cc + 1) & 1][nj] = *(const v8s*)(wfb[nj] + wo);
                }
            }
            int kx = cc >> 2, c4 = cc & 3;
            int xr7 = (l16 + kx) & 7;
            const u16* xb = sm.X + (w_half * 64 + l16 + kx) * XT_LD;
            int xo = (((c4 * 4 + lk) ^ xr7) * 8);
            v8s av[4];
#pragma unroll
            for (int mi = 0; mi < 4; mi++)
                av[mi] = *(const v8s*)(xb + mi * 16 * XT_LD + xo);
#pragma unroll
            for (int mi = 0; mi < 4; mi++)
#pragma unroll
                for (int nj = 0; nj < 4; nj++) {
                    accL[mi][nj] = __builtin_amdgcn_mfma_f32_16x16x32_bf16(
                        av[mi], bL[cc & 1][nj], accL[mi][nj], 0, 0, 0);
                    accF[mi][nj] = __builtin_amdgcn_mfma_f32_16x16x32_bf16(
                        av[mi], bF[cc & 1][nj], accF[mi][nj], 0, 0, 0);
                }
        }
    }
    __syncthreads();   // conv done; X dead, epilogue tiles alias

    float bbL[4], bbF[4];
#pragma unroll
    for (int nj = 0; nj < 4; nj++) {
        bbL[nj] = bcatL[cob + w_co * 64 + nj * 16 + l16];
        bbF[nj] = bfx[cob + w_co * 64 + nj * 16 + l16];
    }

    // ---- per-pixel softmax over 64 g, fully in registers (verified) ----
#pragma unroll
    for (int mi = 0; mi < 4; mi++) {
#pragma unroll
        for (int q = 0; q < 4; q++) {
            float m = accL[mi][0][q] + bbL[0];
#pragma unroll
            for (int nj = 1; nj < 4; nj++) m = fmaxf(m, accL[mi][nj][q] + bbL[nj]);
            m = fmaxf(m, __shfl_xor(m, 1));
            m = fmaxf(m, __shfl_xor(m, 2));
            m = fmaxf(m, __shfl_xor(m, 4));
            m = fmaxf(m, __shfl_xor(m, 8));
            float ssum = 0.f;
#pragma unroll
            for (int nj = 0; nj < 4; nj++) {
                float e = __expf(accL[mi][nj][q] + bbL[nj] - m);
                accL[mi][nj][q] = e; ssum += e;
            }
            ssum += __shfl_xor(ssum, 1);
            ssum += __shfl_xor(ssum, 2);
            ssum += __shfl_xor(ssum, 4);
            ssum += __shfl_xor(ssum, 8);
            float inv = 1.f / ssum;
#pragma unroll
            for (int nj = 0; nj < 4; nj++) accL[mi][nj][q] *= inv;
        }
    }

    // ---- slice_norm: per-wave 64-px reduce, 4 atomics/wave (verified) ----
#pragma unroll
    for (int nj = 0; nj < 4; nj++) {
        float pn = 0.f;
#pragma unroll
        for (int mi = 0; mi < 4; mi++)
#pragma unroll
            for (int q = 0; q < 4; q++) pn += accL[mi][nj][q];
        pn += __shfl_xor(pn, 16);
        pn += __shfl_xor(pn, 32);
        if (lk == 0)
            atomicAdd(&norm[(size_t)(hb + w_co) * GS + nj * 16 + l16], pn);
    }

    // ---- 2 epilogue rounds: one head-pair each (verified per-pair code) ----
#pragma unroll
    for (int hp = 0; hp < 2; hp++) {
        bool mine = ((w_co >> 1) == hp);
        if (mine) {
            int wcp = w_co & 1;
            // scatter sw -> SwT[g][p], fx -> FxT[ch][p] (bf16, swizzled)
#pragma unroll
            for (int nj = 0; nj < 4; nj++) {
                int grow = wcp * 64 + nj * 16 + l16;
                int r7 = l16 & 7;
#pragma unroll
                for (int mi = 0; mi < 4; mi++) {
                    int off = (((w_half * 8 + mi * 2 + (lk >> 1)) ^ r7) * 8) + (lk & 1) * 4;
                    uint2 wv;
                    wv.x = cvtpk(accL[mi][nj][0], accL[mi][nj][1]);
                    wv.y = cvtpk(accL[mi][nj][2], accL[mi][nj][3]);
                    *(uint2*)&sm.e.SwT[grow][off] = wv;
                    uint2 fv;
                    fv.x = cvtpk(accF[mi][nj][0] + bbF[nj], accF[mi][nj][1] + bbF[nj]);
                    fv.y = cvtpk(accF[mi][nj][2] + bbF[nj], accF[mi][nj][3] + bbF[nj]);
                    *(uint2*)&sm.e.FxT[grow][off] = fv;
                }
            }
        }
        __syncthreads();
        if (mine) {
            int wcp = w_co & 1;
            // pooling MFMA: pacc[g][dh] += sum_p SwT[g][p] * FxT[dh][p]
            v4f pacc[2][4];
#pragma unroll
            for (int i = 0; i < 2; i++)
#pragma unroll
                for (int j = 0; j < 4; j++) pacc[i][j] = v4f{0.f, 0.f, 0.f, 0.f};
            int r7 = l16 & 7;
#pragma unroll
            for (int c = 0; c < 4; c++) {
                int ko = (((c * 4 + lk) ^ r7) * 8);
                v8s aw[2], bw[4];
#pragma unroll
                for (int mi = 0; mi < 2; mi++)
                    aw[mi] = *(const v8s*)(&sm.e.SwT[wcp * 64 + w_half * 32 + mi * 16 + l16][0] + ko);
#pragma unroll
                for (int nj = 0; nj < 4; nj++)
                    bw[nj] = *(const v8s*)(&sm.e.FxT[wcp * 64 + nj * 16 + l16][0] + ko);
#pragma unroll
                for (int mi = 0; mi < 2; mi++)
#pragma unroll
                    for (int nj = 0; nj < 4; nj++)
                        pacc[mi][nj] = __builtin_amdgcn_mfma_f32_16x16x32_bf16(
                            aw[mi], bw[nj], pacc[mi][nj], 0, 0, 0);
            }
            int bh2 = hb + 2 * hp + wcp;
#pragma unroll
            for (int mi = 0; mi < 2; mi++)
#pragma unroll
                for (int nj = 0; nj < 4; nj++)
#pragma unroll
                    for (int q = 0; q < 4; q++) {
                        int g = w_half * 32 + mi * 16 + lk * 4 + q;
                        int dh = nj * 16 + l16;
                        atomicAdd(&straw[((size_t)bh2 * GS + g) * DH + dh], pacc[mi][nj][q]);
                    }
        }
        // swbT store: [bh][g][n], all 8 waves, coalesced 16B chunks
#pragma unroll
        for (int it = 0; it < 4; it++) {
            int chunk = it * 512 + t;     // 0..2047
            int gi = chunk >> 4;          // 0..127 (head-in-pair = gi>>6)
            int p8 = chunk & 15;
            uint4 v = *(const uint4*)(&sm.e.SwT[gi][0] + ((p8 ^ (gi & 7)) * 8));
            size_t di = (((size_t)(hb + 2 * hp + (gi >> 6)) * GS + (gi & 63)) * NPIX)
                        + (size_t)y * WM + p8 * 8;
            *(uint4*)&swbT[di] = v;
        }
        __syncthreads();   // SwT/FxT reused next round
    }
}

// ---------------------------------------------------------------------------
// K4: per-(b,h) attention -> M1 (unchanged, verified).
// ---------------------------------------------------------------------------
__global__ __launch_bounds__(256) void k_attn(
    const float* __restrict__ straw, const float* __restrict__ norm,
    const float* __restrict__ wq, const float* __restrict__ wk, const float* __restrict__ wv,
    const float* __restrict__ outw, float* __restrict__ m1)
{
    __shared__ float lds[4][64][64];
    int bh = blockIdx.x, h = bh & 7;
    int t = threadIdx.x;
    for (int i = t; i < 4096; i += 256) {
        int g = i >> 6;
        lds[0][g][i & 63] = straw[(size_t)bh * 4096 + i] / (norm[bh * 64 + g] + 1e-5f);
    }
    __syncthreads();
    int g = t >> 2, d0 = (t & 3) << 4;
    for (int d = d0; d < d0 + 16; d++) {
        float sq = 0.f, sk = 0.f, sv = 0.f;
        for (int c = 0; c < 64; c++) {
            float sc = lds[0][g][c];
            sq = fmaf(sc, wq[d * 64 + c], sq);
            sk = fmaf(sc, wk[d * 64 + c], sk);
            sv = fmaf(sc, wv[d * 64 + c], sv);
        }
        lds[1][g][d] = sq; lds[2][g][d] = sk; lds[3][g][d] = sv;
    }
    __syncthreads();
    float attnrow[16];
    for (int k2 = d0, i = 0; k2 < d0 + 16; k2++, i++) {
        float s = 0.f;
        for (int d = 0; d < 64; d++) s = fmaf(lds[1][g][d], lds[2][k2][d], s);
        attnrow[i] = s * 0.125f;
    }
    __syncthreads();
    for (int i = 0; i < 16; i++) lds[0][g][d0 + i] = attnrow[i];
    __syncthreads();
    if (t < 64) {
        float mx = -1e30f;
        for (int j = 0; j < 64; j++) mx = fmaxf(mx, lds[0][t][j]);
        float s = 0.f;
        for (int j = 0; j < 64; j++) { float e = __expf(lds[0][t][j] - mx); lds[0][t][j] = e; s += e; }
        float inv = 1.f / s;
        for (int j = 0; j < 64; j++) lds[0][t][j] *= inv;
    }
    __syncthreads();
    float osrow[16];
    for (int d = d0, i = 0; d < d0 + 16; d++, i++) {
        float s = 0.f;
        for (int kx = 0; kx < 64; kx++) s = fmaf(lds[0][g][kx], lds[3][kx][d], s);
        osrow[i] = s;
    }
    __syncthreads();
    for (int i = 0; i < 16; i++) lds[2][g][d0 + i] = osrow[i];
    __syncthreads();
    int dimb = (t & 3) << 5;
    for (int dim = dimb; dim < dimb + 32; dim++) {
        float s = 0.f;
        for (int c = 0; c < 64; c++)
            s = fmaf(lds[2][g][c], outw[(size_t)dim * INNER + h * 64 + c], s);
        m1[((size_t)bh * 64 + g) * DIMC + dim] = s;
    }
}

// ---------------------------------------------------------------------------
// K5: out[b][n][d] = sum_{h,g} swT[bh][g][n] * M1[bh][g][d] + out_b[d]
// (unchanged, verified).
// ---------------------------------------------------------------------------
__global__ __launch_bounds__(256) void k_final(
    const u16* __restrict__ swbT, const float* __restrict__ m1,
    const float* __restrict__ outb, float* __restrict__ out)
{
    __shared__ float As[32][68];    // sw^T: [g][n]
    __shared__ float Bs[32][128];   // M1:   [g][d]
    int b = blockIdx.x, nt = blockIdx.y;
    int t = threadIdx.x;
    int tn = t & 15, tm = t >> 4;
    float acc[4][8];
#pragma unroll
    for (int i = 0; i < 4; i++)
#pragma unroll
        for (int j = 0; j < 8; j++) acc[i][j] = 0.f;
    int n0 = nt * 64;
    int gg = t >> 3, nq = (t & 7) * 8;
    int g2 = t >> 3, dd = (t & 7) * 16;
    for (int h = 0; h < HEADS; h++) {
        const u16* swp = swbT + (size_t)(b * HEADS + h) * GS * NPIX;
        const float* m1p = m1 + (size_t)(b * HEADS + h) * GS * DIMC;
        for (int g0 = 0; g0 < 64; g0 += 32) {
            __syncthreads();
            BF8 av8; av8.v = *(const uint4*)&swp[(size_t)(g0 + gg) * NPIX + n0 + nq];
#pragma unroll
            for (int i = 0; i < 8; i++) As[gg][nq + i] = bf2f(av8.s[i]);
            const float* bp = m1p + (size_t)(g0 + g2) * DIMC + dd;
            *(float4*)&Bs[g2][dd + 0]  = *(const float4*)(bp + 0);
            *(float4*)&Bs[g2][dd + 4]  = *(const float4*)(bp + 4);
            *(float4*)&Bs[g2][dd + 8]  = *(const float4*)(bp + 8);
            *(float4*)&Bs[g2][dd + 12] = *(const float4*)(bp + 12);
            __syncthreads();
#pragma unroll
            for (int kk = 0; kk < 32; kk++) {
                float4 a = *(const float4*)&As[kk][tm * 4];
                float4 b0 = *(const float4*)&Bs[kk][tn * 4];
                float4 b1 = *(const float4*)&Bs[kk][tn * 4 + 64];
                float av[4] = {a.x, a.y, a.z, a.w};
                float bv[8] = {b0.x, b0.y, b0.z, b0.w, b1.x, b1.y, b1.z, b1.w};
#pragma unroll
                for (int i = 0; i < 4; i++)
#pragma unroll
                    for (int j = 0; j < 8; j++)
                        acc[i][j] = fmaf(av[i], bv[j], acc[i][j]);
            }
        }
    }
    float4 bias0 = *(const float4*)&outb[tn * 4];
    float4 bias1 = *(const float4*)&outb[64 + tn * 4];
#pragma unroll
    for (int i = 0; i < 4; i++) {
        size_t n = (size_t)n0 + tm * 4 + i;
        size_t rb = ((size_t)b * NPIX + n) * DIMC;
        float4 r0, r1;
        r0.x = acc[i][0] + bias0.x; r0.y = acc[i][1] + bias0.y;
        r0.z = acc[i][2] + bias0.z; r0.w = acc[i][3] + bias0.w;
        r1.x = acc[i][4] + bias1.x; r1.y = acc[i][5] + bias1.y;
        r1.z = acc[i][6] + bias1.z; r1.w = acc[i][7] + bias1.w;
        *(float4*)&out[rb + tn * 4] = r0;
        *(float4*)&out[rb + 64 + tn * 4] = r1;
    }
}

// ---------------------------------------------------------------------------
extern "C" void kernel_launch(void* const* d_in, const int* in_sizes, int n_in,
                              void* d_out, int out_size, void* d_ws, size_t ws_size,
                              hipStream_t stream)
{
    (void)in_sizes; (void)n_in; (void)out_size;
    const float* x    = (const float*)d_in[0];
    const float* wfx  = (const float*)d_in[1];
    const float* bfx  = (const float*)d_in[2];
    const float* wx   = (const float*)d_in[3];
    const float* bx   = (const float*)d_in[4];
    const float* slw  = (const float*)d_in[5];
    const float* slb  = (const float*)d_in[6];
    const float* temp = (const float*)d_in[7];
    const float* wq   = (const float*)d_in[8];
    const float* wk   = (const float*)d_in[9];
    const float* wv   = (const float*)d_in[10];
    const float* outw = (const float*)d_in[11];
    const float* outb = (const float*)d_in[12];
    float* out = (float*)d_out;
    float* W = (float*)d_ws;

    // workspace layout (float offsets) — identical footprint to verified round-4
    u16*   wcatT = (u16*)W;               // 589,824 u16
    u16*   wfxT  = (u16*)(W + 294912);    // 589,824 u16
    float* bcatL = W + 589824;            //       512
    float* norm  = W + 590336;            //     4,096   (zeroed)
    float* straw = W + 594432;            //   262,144   (zeroed, contiguous w/ norm)
    float* m1    = W + 856576;            //   524,288
    u16*   swbT  = (u16*)(W + 1380864);   // 67,108,864 u16 = 128 MiB, [bh][g][n]
    const size_t need = 1380864ull * 4 + 67108864ull * 2;   // 139,741,184 B
    if (ws_size < need) return;

    hipMemsetAsync(norm, 0, (4096 + 262144) * sizeof(float), stream);

    k_build_w<<<dim3(1152), 256, 0, stream>>>(wx, wfx, slw, temp, wcatT, wfxT);
    k_build_b<<<dim3(1), 512, 0, stream>>>(bx, slw, slb, temp, bcatL);
    k_conv2<<<dim3(1024, 2), 512, 0, stream>>>(x, wcatT, wfxT, bcatL, bfx, swbT, straw, norm);
    k_attn<<<dim3(64), 256, 0, stream>>>(straw, norm, wq, wk, wv, outw, m1);
    k_final<<<dim3(8, 256), 256, 0, stream>>>(swbT, m1, outb, out);
}